// Round 12
// baseline (500.201 us; speedup 1.0000x reference)
//
#include <hip/hip_runtime.h>
#include <math.h>

// ---------------------------------------------------------------------------
// 2-step recurrent attention cell, N=8, I=128, C=Hc=A=P=O=256, H=W=40
// (Q=1600), VALID 3x3 -> 38x38 (D=1444). fp32 reference.
//
// R0-R10: algebraic reductions, MFMA GEMMs, DMA staging + XOR swizzle,
// direct shifted-tap conv, fp16 single-plane, 72-row classed GEMMs.
// R11-R13 FAILED (journal). R14 WIN (529->460): 64x128 tile.
// R15/R16 FAILED: BK=128 / dbuf@48KB (occupancy loss dominates).
// R17 WIN (460->442): 64x64+static dbuf @32KB. R18: qk on 64x128 single-buf.
// R19 WIN (->436.6): counted-vmcnt T4 on 64x64 dbuf + named wrappers.
// R20 FAILED-BRANCH: qk 64x128 dbuf+T4 @48KB (occupancy loss). qk CONVERGED
// at ~60us in R14 single-buf geometry.
// R21 NEUTRAL (437.2): classed-chain fusion correct but launch overhead ~0.
// R22: G13 instruction-level fixes in the memory-bound tail:
// (a) softmax_h16 vectorized: h8 loads/stores, register-resident row chunk,
//     masked 1444-tail (cols 1444..1471 of scL16 are never written).
// (b) xT transpose out of prep_all into LDS-tiled xt_kern (64q x 128i1,
//     Tl[128][65] pad -> conflict-free both phases, float4 reads).
// ---------------------------------------------------------------------------

typedef _Float16 f16;
typedef _Float16 h8 __attribute__((ext_vector_type(8)));   // 8 fp16 (4 VGPRs)
typedef __attribute__((ext_vector_type(4))) float f4;

__device__ __forceinline__ ushort f2h(float f) {
  union { f16 h; ushort u; } cv; cv.h = (f16)f; return cv.u;
}
__device__ __forceinline__ float h2f(ushort u) {
  union { ushort u; f16 h; } cv; cv.u = u; return (float)cv.h;
}

// ---------------- MFMA fp16 GEMM, 64x64 tile, counted-vmcnt dbuf -----------
// (R19 structure, unchanged.) C[m][n] = sum_k A[m][k]*B[n][k].
struct MgArgs {
  const ushort* A; long sAb;
  const ushort* B; long sBb;
  int M, Nn, K, Krow, mode, gRow0, swap, aConv, bConv;
  const ushort* zp;
  float* Y; long sYb, sYm; int nPer; long sYb2;
  const float* bias; int biasN;
  ushort* Yh; long sYpb, sYpm, pOff;
  ushort* Y2h;
};

__device__ __forceinline__ void mg_body(const MgArgs& g, ushort* lbase)
{
  const int bz = blockIdx.z;
  const ushort* __restrict__ A = g.A + (long)bz * g.sAb;
  const ushort* __restrict__ B = g.B + (long)bz * g.sBb;
  const int mb = g.swap ? blockIdx.y : blockIdx.x;
  const int nb = g.swap ? blockIdx.x : blockIdx.y;
  const int m0 = mb * 64, n0 = nb * 64;
  const int t = threadIdx.x;
  const int lane = t & 63, wv = t >> 6;
  const int r = lane & 15, qd = lane >> 4;
  const int wn = wv * 16;
  const int lrow = lane >> 3, lch = lane & 7;
  f4 acc[4];
  #pragma unroll
  for (int i = 0; i < 4; ++i) acc[i] = (f4){0.f, 0.f, 0.f, 0.f};

  const int cg8 = (lch ^ lrow) * 8;
  int aB[2], aY[2], aX[2]; long aO[2];
  int bB[2], bY[2], bX[2]; long bO[2];
  #pragma unroll
  for (int i = 0; i < 2; ++i) {        // A rows: wv*16 + i*8 + lrow (0..63)
    int gr = m0 + wv * 16 + i * 8 + lrow;
    if (g.aConv) {
      int n8 = gr / 1600, pos = gr - n8 * 1600;
      int py = pos / 40, px = pos - py * 40;
      aB[i] = n8 * 1600; aY[i] = py; aX[i] = px;
    } else { if (gr > g.M - 1) gr = g.M - 1; aO[i] = (long)gr * g.Krow; }
  }
  #pragma unroll
  for (int i = 0; i < 2; ++i) {        // B rows: wv*16 + i*8 + lrow (0..63)
    int gr = n0 + wv * 16 + i * 8 + lrow;
    if (g.bConv) {
      int n8 = gr / 1600, pos = gr - n8 * 1600;
      int py = pos / 40, px = pos - py * 40;
      bB[i] = n8 * 1600; bY[i] = py; bX[i] = px;
    } else { if (gr > g.Nn - 1) gr = g.Nn - 1; bO[i] = (long)gr * g.Krow; }
  }

  auto stage = [&](int ch, int lb) {
    int cb = ch / 9, tap = ch - cb * 9;       // conv-K: cb-major, tap-minor
    int tdy = tap / 3 - 1, tdx = tap - (tap / 3) * 3 - 1;
    int kin = cb << 6;
    int kc2 = ch << 6;
    #pragma unroll
    for (int i = 0; i < 2; ++i) {             // A (2 x 16B per thread)
      const ushort* p; size_t go;
      if (g.aConv) {
        int yy = aY[i] + tdy, xx = aX[i] + tdx;
        bool v = ((unsigned)yy < 40u) && ((unsigned)xx < 40u);
        if (v) { go = (size_t)(aB[i] + yy * 40 + xx) * 768 + kin + cg8; p = A; }
        else   { go = 0; p = g.zp; }
      } else { go = (size_t)(aO[i] + kc2 + cg8); p = A; }
      __builtin_amdgcn_global_load_lds(p + go, lbase + lb + wv * 1024 + i * 512, 16, 0, 0);
    }
    #pragma unroll
    for (int i = 0; i < 2; ++i) {             // B (2 x 16B per thread)
      const ushort* p; size_t go;
      if (g.bConv) {
        int yy = bY[i] + tdy, xx = bX[i] + tdx;
        bool v = ((unsigned)yy < 40u) && ((unsigned)xx < 40u);
        if (v) { go = (size_t)(bB[i] + yy * 40 + xx) * 768 + kin + cg8; p = B; }
        else   { go = 0; p = g.zp; }
      } else { go = (size_t)(bO[i] + kc2 + cg8); p = B; }
      __builtin_amdgcn_global_load_lds(p + go, lbase + lb + 4096 + wv * 1024 + i * 512, 16, 0, 0);
    }
  };

  auto compute = [&](int lb) {
    #pragma unroll
    for (int kk = 0; kk < 2; ++kk) {
      int off = (((kk << 2) + qd) ^ (r & 7)) << 3;
      h8 af[4], bf;
      #pragma unroll
      for (int mt = 0; mt < 4; ++mt)
        af[mt] = *(const h8*)&lbase[lb + (mt * 16 + r) * 64 + off];
      bf = *(const h8*)&lbase[lb + 4096 + (wn + r) * 64 + off];
      #pragma unroll
      for (int mt = 0; mt < 4; ++mt)
        acc[mt] = __builtin_amdgcn_mfma_f32_16x16x32_f16(af[mt], bf, acc[mt], 0, 0, 0);
    }
  };

  // counted-vmcnt 2-phase (T4): never drain vmcnt to 0 mid-loop.
  const int nch = g.K >> 6;
  stage(0, 0);                                  // out: ch0(4)
  int ch = 0;
  while (ch + 2 <= nch) {
    stage(ch + 1, 8192);                        // out: ch(4)+ch1(4)
    asm volatile("s_waitcnt vmcnt(4)" ::: "memory");   // ch landed
    __builtin_amdgcn_s_barrier();
    __builtin_amdgcn_sched_barrier(0);
    compute(0);
    __builtin_amdgcn_s_barrier();               // WAR: reads of b0 done
    __builtin_amdgcn_sched_barrier(0);
    if (ch + 2 < nch) {
      stage(ch + 2, 0);                         // out: ch1(<=4)+ch2(4)
      asm volatile("s_waitcnt vmcnt(4)" ::: "memory"); // ch+1 landed
    } else {
      asm volatile("s_waitcnt vmcnt(0)" ::: "memory"); // no new loads issued
    }
    __builtin_amdgcn_s_barrier();
    __builtin_amdgcn_sched_barrier(0);
    compute(8192);
    __builtin_amdgcn_s_barrier();               // WAR: reads of b1 done
    __builtin_amdgcn_sched_barrier(0);
    ch += 2;
  }
  if (ch < nch) {                               // odd tail (staged into b0)
    asm volatile("s_waitcnt vmcnt(0)" ::: "memory");
    __builtin_amdgcn_s_barrier();
    __builtin_amdgcn_sched_barrier(0);
    compute(0);
  }

  #pragma unroll
  for (int mt = 0; mt < 4; ++mt) {
    int nn = n0 + wn + r;
    if (nn >= g.Nn) continue;
    #pragma unroll
    for (int e = 0; e < 4; ++e) {
      int mm = m0 + mt * 16 + qd * 4 + e;
      if (mm >= g.M) continue;
      float v = acc[mt][e];
      if (g.mode == 0) {
        if (g.bias) v += g.bias[mm];
        int b2 = nn / g.nPer, nq = nn - b2 * g.nPer;
        g.Y[(size_t)bz * g.sYb + (size_t)b2 * g.sYb2 + (size_t)mm * g.sYm + nq] = v;
      } else if (g.mode == 1) {
        if (g.bias) v += g.bias[g.biasN ? nn : mm];
        g.Yh[(size_t)bz * g.sYpb + (size_t)mm * g.sYpm + nn + g.pOff] = f2h(v);
      } else if (g.mode == 2) {
        int gm = g.gRow0 + mm;
        int n8 = gm / 1600, q = gm - n8 * 1600;
        ushort h = f2h(v);
        if (nn < 256) {
          g.Yh[(size_t)n8 * 409600 + (size_t)q * 256 + nn] = h;
        } else {
          int qy = q / 40, qx = q - qy * 40;
          if (qy >= 1 && qy <= 38 && qx >= 1 && qx <= 38)
            g.Y2h[(size_t)n8 * 369664 + (size_t)((qy - 1) * 38 + qx - 1) * 256 + (nn - 256)] = h;
        }
      } else {   // mode 3
        int gn = g.gRow0 + nn;
        int n8 = gn / 1600, q = gn - n8 * 1600;
        int qy = q / 40, qx = q - qy * 40;
        if (qy >= 1 && qy <= 38 && qx >= 1 && qx <= 38)
          g.Yh[(size_t)n8 * 376832 + (size_t)mm * 1472 + (qy - 1) * 38 + qx - 1] = f2h(v);
      }
    }
  }
}

// named wrappers: one per call site for rocprof attribution
#define MG_KERN(name) \
__global__ __launch_bounds__(256) void name(MgArgs g) { \
  __shared__ ushort S[16384]; mg_body(g, S); }
MG_KERN(mg_xp)
MG_KERN(mg_v)
MG_KERN(mg_cls)
MG_KERN(mg_lg)
MG_KERN(mg_pv)
MG_KERN(mg_out)
#undef MG_KERN

// ---------------- MFMA fp16 GEMM, 64x128 tile, single-buf (R14) ------------
// qk-conv only. CONVERGED at ~60.5us across 6 tested structures: occupancy
// (24KB LDS, ~2.7 blocks/CU) beats every pipelining variant on this shape.
__global__ __launch_bounds__(256) void mgemm_w(
    const ushort* __restrict__ A, long sAb,
    const ushort* __restrict__ B, long sBb,
    int M, int Nn, int K, int Krow, int mode, int gRow0, int swap,
    int aConv, int bConv,
    const ushort* __restrict__ zp,
    float* __restrict__ Y, long sYb, long sYm, int nPer, long sYb2,
    const float* __restrict__ bias, int biasN,
    ushort* __restrict__ Yh, long sYpb, long sYpm, long pOff,
    ushort* __restrict__ Y2h)
{
  __shared__ ushort S[12288];   // SA[64][64] @ 0, SB[128][64] @ 4096 ; 24 KB
  const int bz = blockIdx.z;
  A += (long)bz * sAb;
  B += (long)bz * sBb;
  const int mb = swap ? blockIdx.y : blockIdx.x;
  const int nb = swap ? blockIdx.x : blockIdx.y;
  const int m0 = mb * 64, n0 = nb * 128;
  const int t = threadIdx.x;
  const int lane = t & 63, wv = t >> 6;
  const int r = lane & 15, qd = lane >> 4;
  const int wn = wv * 32;
  const int lrow = lane >> 3, lch = lane & 7;
  f4 acc[4][2];
  #pragma unroll
  for (int i = 0; i < 4; ++i)
    #pragma unroll
    for (int j = 0; j < 2; ++j) acc[i][j] = (f4){0.f, 0.f, 0.f, 0.f};

  const int cg8 = (lch ^ lrow) * 8;
  int aB[2], aY[2], aX[2]; long aO[2];
  int bB[4], bY[4], bX[4]; long bO[4];
  #pragma unroll
  for (int i = 0; i < 2; ++i) {        // A rows: wv*16 + i*8 + lrow (0..63)
    int gr = m0 + wv * 16 + i * 8 + lrow;
    if (aConv) {
      int n8 = gr / 1600, pos = gr - n8 * 1600;
      int py = pos / 40, px = pos - py * 40;
      aB[i] = n8 * 1600; aY[i] = py; aX[i] = px;
    } else { if (gr > M - 1) gr = M - 1; aO[i] = (long)gr * Krow; }
  }
  #pragma unroll
  for (int i = 0; i < 4; ++i) {        // B rows: wv*32 + i*8 + lrow (0..127)
    int gr = n0 + wv * 32 + i * 8 + lrow;
    if (bConv) {
      int n8 = gr / 1600, pos = gr - n8 * 1600;
      int py = pos / 40, px = pos - py * 40;
      bB[i] = n8 * 1600; bY[i] = py; bX[i] = px;
    } else { if (gr > Nn - 1) gr = Nn - 1; bO[i] = (long)gr * Krow; }
  }

  ushort* lbase = S;
  for (int kc = 0; kc < K; kc += 64) {
    __syncthreads();
    int ch = kc >> 6;
    int cb = ch / 9, tap = ch - cb * 9;       // conv-K: cb-major, tap-minor
    int tdy = tap / 3 - 1, tdx = tap - (tap / 3) * 3 - 1;
    int kin = cb << 6;
    #pragma unroll
    for (int i = 0; i < 2; ++i) {             // stage A (2 x 16B per thread)
      const ushort* p; size_t go;
      if (aConv) {
        int yy = aY[i] + tdy, xx = aX[i] + tdx;
        bool v = ((unsigned)yy < 40u) && ((unsigned)xx < 40u);
        if (v) { go = (size_t)(aB[i] + yy * 40 + xx) * 768 + kin + cg8; p = A; }
        else   { go = 0; p = zp; }
      } else { go = (size_t)(aO[i] + kc + cg8); p = A; }
      __builtin_amdgcn_global_load_lds(p + go, lbase + wv * 1024 + i * 512, 16, 0, 0);
    }
    #pragma unroll
    for (int i = 0; i < 4; ++i) {             // stage B (4 x 16B per thread)
      const ushort* p; size_t go;
      if (bConv) {
        int yy = bY[i] + tdy, xx = bX[i] + tdx;
        bool v = ((unsigned)yy < 40u) && ((unsigned)xx < 40u);
        if (v) { go = (size_t)(bB[i] + yy * 40 + xx) * 768 + kin + cg8; p = B; }
        else   { go = 0; p = zp; }
      } else { go = (size_t)(bO[i] + kc + cg8); p = B; }
      __builtin_amdgcn_global_load_lds(p + go, lbase + 4096 + wv * 2048 + i * 512, 16, 0, 0);
    }
    __syncthreads();
    #pragma unroll
    for (int kk = 0; kk < 2; ++kk) {
      int off = (((kk << 2) + qd) ^ (r & 7)) << 3;
      h8 af[4], bf[2];
      #pragma unroll
      for (int mt = 0; mt < 4; ++mt)
        af[mt] = *(const h8*)&lbase[(mt * 16 + r) * 64 + off];
      #pragma unroll
      for (int nt = 0; nt < 2; ++nt)
        bf[nt] = *(const h8*)&lbase[4096 + (wn + nt * 16 + r) * 64 + off];
      #pragma unroll
      for (int mt = 0; mt < 4; ++mt)
        #pragma unroll
        for (int nt = 0; nt < 2; ++nt)
          acc[mt][nt] = __builtin_amdgcn_mfma_f32_16x16x32_f16(af[mt], bf[nt], acc[mt][nt], 0, 0, 0);
    }
  }
  #pragma unroll
  for (int mt = 0; mt < 4; ++mt)
    #pragma unroll
    for (int nt = 0; nt < 2; ++nt) {
      int nn = n0 + wn + nt * 16 + r;
      if (nn >= Nn) continue;
      #pragma unroll
      for (int e = 0; e < 4; ++e) {
        int mm = m0 + mt * 16 + qd * 4 + e;
        if (mm >= M) continue;
        float v = acc[mt][nt][e];
        if (mode == 0) {
          if (bias) v += bias[mm];
          int b2 = nn / nPer, nq = nn - b2 * nPer;
          Y[(size_t)bz * sYb + (size_t)b2 * sYb2 + (size_t)mm * sYm + nq] = v;
        } else if (mode == 1) {
          if (bias) v += bias[biasN ? nn : mm];
          Yh[(size_t)bz * sYpb + (size_t)mm * sYpm + nn + pOff] = f2h(v);
        } else if (mode == 2) {
          int gm = gRow0 + mm;
          int n8 = gm / 1600, q = gm - n8 * 1600;
          ushort h = f2h(v);
          if (nn < 256) {
            Yh[(size_t)n8 * 409600 + (size_t)q * 256 + nn] = h;
          } else {
            int qy = q / 40, qx = q - qy * 40;
            if (qy >= 1 && qy <= 38 && qx >= 1 && qx <= 38)
              Y2h[(size_t)n8 * 369664 + (size_t)((qy - 1) * 38 + qx - 1) * 256 + (nn - 256)] = h;
          }
        } else {   // mode 3
          int gn = gRow0 + nn;
          int n8 = gn / 1600, q = gn - n8 * 1600;
          int qy = q / 40, qx = q - qy * 40;
          if (qy >= 1 && qy <= 38 && qx >= 1 && qx <= 38)
            Yh[(size_t)n8 * 376832 + (size_t)mm * 1472 + (qy - 1) * 38 + qx - 1] = f2h(v);
        }
      }
    }
}

// ---------------- xT transpose: x [8][128][1600] f32 -> xT [12800][128] f16
// LDS-tiled (R22): 64q x 128i1 per block; Tl[128][65] (+1 pad) makes both
// the write phase (2-way) and read phase (stride 65 == 1 mod 32) conflict-
// free. float4-coalesced global reads; lane-contiguous fp16 stores.
__global__ __launch_bounds__(256) void xt_kern(
    const float* __restrict__ x, ushort* __restrict__ xT)
{
  __shared__ float Tl[128][65];
  int qt = blockIdx.x * 64, n8 = blockIdx.y;
  int t = threadIdx.x;
  int qi = (t & 15) * 4;       // 0..60
  int i1b = t >> 4;            // 0..15
  #pragma unroll
  for (int ps = 0; ps < 8; ++ps) {
    int i1 = i1b + ps * 16;
    const float* xp = x + ((long)n8 * 128 + i1) * 1600 + qt + qi;
    float4 v = *(const float4*)xp;
    Tl[i1][qi] = v.x; Tl[i1][qi + 1] = v.y; Tl[i1][qi + 2] = v.z; Tl[i1][qi + 3] = v.w;
  }
  __syncthreads();
  int i1 = t & 127, qb = t >> 7;   // qb 0..1
  #pragma unroll
  for (int ps = 0; ps < 32; ++ps) {
    int qq = qb + ps * 2;
    xT[((long)n8 * 1600 + qt + qq) * 128 + i1] = f2h(Tl[i1][qq]);
  }
}

// ---------------- fused prep: weight conversions + pads (xT moved out) -----
__global__ __launch_bounds__(256) void prep_all(
    const float* __restrict__ w_qx, const float* __restrict__ w_kx,
    const float* __restrict__ w_vx,
    const float* __restrict__ w_px, const float* __restrict__ w_out,
    const float* __restrict__ w_kh, const float* __restrict__ w_vh,
    const float* __restrict__ w_z, const float* __restrict__ w_h,
    ushort* __restrict__ Wqk, ushort* __restrict__ Wv,
    ushort* __restrict__ wpx, ushort* __restrict__ wout,
    ushort* __restrict__ Wkv, ushort* __restrict__ Wzh,
    ushort* __restrict__ zp, ushort* __restrict__ vxp)
{
  long gi = (long)blockIdx.x * 256 + threadIdx.x;
  if (gi < 64) zp[gi] = 0;
  long i = gi;
  if (i < 1769472) {                         // Wqk/Wv conv-K reorder
    int o = (int)(i / 2304), k = (int)(i - (long)o * 2304);
    int cb = k / 576, rem = k - cb * 576;
    int tap = rem >> 6, ci = rem & 63;
    int si = (cb * 64 + ci) * 9 + tap;
    float f; ushort* d; int oo;
    if (o < 256)      { f = w_qx[o * 2304 + si];         d = Wqk; oo = o; }
    else if (o < 512) { f = w_kx[(o - 256) * 2304 + si]; d = Wqk; oo = o; }
    else              { f = w_vx[(o - 512) * 2304 + si]; d = Wv;  oo = o - 512; }
    d[oo * 2304 + k] = f2h(f);
    return;
  }
  i -= 1769472;
  if (i < 32768)  { wpx[i]  = f2h(w_px[i]);  return; }
  i -= 32768;
  if (i < 196608) { wout[i] = f2h(w_out[i]); return; }
  i -= 196608;
  if (i < 1179648) { Wkv[i] = f2h(i < 589824 ? w_kh[i] : w_vh[i - 589824]); return; }
  i -= 1179648;
  if (i < 262144)  { Wzh[i] = f2h(i < 131072 ? w_z[i] : w_h[i - 131072]); return; }
  i -= 262144;
  if (i < 57344) {                           // vxp pad cols 1444..1471
    int j = (int)(i % 28); int rr = (int)(i / 28);
    int c = rr % 256, n = rr / 256;
    vxp[(size_t)n * 376832 + (size_t)c * 1472 + 1444 + j] = 0;
  }
}

// step-1 uniform-h class tables
__global__ __launch_bounds__(64) void uniform_kv_kern(
    const float* __restrict__ h0, const float* __restrict__ w_qh,
    const float* __restrict__ w_kh, const float* __restrict__ w_vh,
    float* __restrict__ qh1, float* __restrict__ kh1, float* __restrict__ vh1)
{
  int a = blockIdx.x, j = blockIdx.y, t = threadIdx.x;
  const float* wsel = (j < 9) ? w_qh : (j == 9) ? w_kh : w_vh;
  bool dyok0 = true, dyok2 = true, dxok0 = true, dxok2 = true;
  if (j < 9) {
    int uy = j / 3, ux = j - uy * 3;
    dyok0 = (uy != 0); dyok2 = (uy != 2);
    dxok0 = (ux != 0); dxok2 = (ux != 2);
  }
  float acc = 0.f;
  for (int c = t; c < 256; c += 64) {
    const float* wp = wsel + a * 2304 + c * 9;
    float s = 0.f;
    #pragma unroll
    for (int dy = 0; dy < 3; ++dy) {
      if ((dy == 0 && !dyok0) || (dy == 2 && !dyok2)) continue;
      #pragma unroll
      for (int dx = 0; dx < 3; ++dx) {
        if ((dx == 0 && !dxok0) || (dx == 2 && !dxok2)) continue;
        s += wp[dy * 3 + dx];
      }
    }
    acc += s * h0[c];
  }
  #pragma unroll
  for (int o = 32; o; o >>= 1) acc += __shfl_down(acc, o);
  if (t == 0) {
    if (j < 9) qh1[j * 256 + a] = acc;
    else if (j == 9) kh1[a] = acc;
    else vh1[a] = acc;
  }
}

// L0[n][u][d] = sum_c qh1[u][c] * k_x[n][d][c]  (kxT fp16) -- raw logits
__global__ __launch_bounds__(256) void l0_logits(
    const float* __restrict__ qh1, const ushort* __restrict__ kxT,
    float* __restrict__ L0)
{
  __shared__ float qs[2304];
  int db = blockIdx.x, n = blockIdx.y;
  for (int i = threadIdx.x; i < 2304; i += 256) qs[i] = qh1[i];
  __syncthreads();
  int d = db * 256 + threadIdx.x;
  bool act = d < 1444;
  const ushort* vp = kxT + (size_t)n * 369664 + (act ? (size_t)d * 256 : 0);
  float acc[9] = {0.f,0.f,0.f,0.f,0.f,0.f,0.f,0.f,0.f};
  for (int c8 = 0; c8 < 256; c8 += 8) {
    h8 v = *(const h8*)(const void*)(vp + c8);
    #pragma unroll
    for (int j = 0; j < 8; ++j) {
      float f = (float)v[j];
      #pragma unroll
      for (int u = 0; u < 9; ++u) acc[u] += qs[u * 256 + c8 + j] * f;
    }
  }
  if (act)
    for (int u = 0; u < 9; ++u) L0[n * 12996 + u * 1444 + d] = acc[u];
}

// FUSED (R21): row-softmax over raw L0[n][u][:1444] + PV vs vxp + AV write.
__global__ __launch_bounds__(256) void a10_pv_av(
    const float* __restrict__ L0, const ushort* __restrict__ vxp,
    const float* __restrict__ vh1, ushort* __restrict__ AV)
{
  int u = blockIdx.x, n = blockIdx.y;
  __shared__ float wts[1472];
  __shared__ float redm[4], reds[4];
  const float* wrow = L0 + n * 12996 + u * 1444;
  int t = threadIdx.x;
  float mx = -3.4e38f;
  for (int i = t; i < 1444; i += 256) { float v = wrow[i]; wts[i] = v; mx = fmaxf(mx, v); }
  #pragma unroll
  for (int o = 32; o; o >>= 1) mx = fmaxf(mx, __shfl_down(mx, o));
  if ((t & 63) == 0) redm[t >> 6] = mx;
  __syncthreads();
  mx = fmaxf(fmaxf(redm[0], redm[1]), fmaxf(redm[2], redm[3]));
  float s = 0.f;
  for (int i = t; i < 1444; i += 256) { float v = expf(wts[i] - mx); wts[i] = v; s += v; }
  #pragma unroll
  for (int o = 32; o; o >>= 1) s += __shfl_down(s, o);
  if ((t & 63) == 0) reds[t >> 6] = s;
  __syncthreads();
  float inv = 1.f / (reds[0] + reds[1] + reds[2] + reds[3]);
  for (int i = t; i < 1444; i += 256) wts[i] *= inv;
  if (t < 28) wts[1444 + t] = 0.f;
  __syncthreads();
  int p = t;
  const ushort* vp = vxp + (size_t)n * 376832 + (size_t)p * 1472;
  float acc = 0.f;
  for (int d8 = 0; d8 < 1472; d8 += 8) {
    h8 v = *(const h8*)(const void*)(vp + d8);
    #pragma unroll
    for (int j = 0; j < 8; ++j) acc += wts[d8 + j] * (float)v[j];
  }
  size_t row = (size_t)(n * 9 + u);
  AV[row * 512 + p] = f2h(acc);
  AV[row * 512 + 256 + p] = f2h(vh1[p]);
}

// gate tail: sum 4 K-slice partials pre72p[4][72][512], bias, GRU blend
__global__ __launch_bounds__(256) void gate_ew2(
    const float* __restrict__ pre72p, const float* __restrict__ b_z,
    const float* __restrict__ b_h, const float* __restrict__ h0,
    float* __restrict__ h1)
{
  int i = blockIdx.x * 256 + threadIdx.x;
  if (i >= 72 * 256) return;
  int row = i >> 8, c = i & 255;
  float zs = 0.f, hs = 0.f;
  #pragma unroll
  for (int s = 0; s < 4; ++s) {
    zs += pre72p[s * 36864 + row * 512 + c];
    hs += pre72p[s * 36864 + row * 512 + 256 + c];
  }
  float z = 1.f / (1.f + expf(-(zs + b_z[c])));
  float hv = tanhf(hs + b_h[c]);
  int n = row / 9, u = row - n * 9;
  h1[n * 2304 + c * 9 + u] = z * h0[c] + (1.f - z) * hv;
}

// GA[72][2304] fp16: classed im2col of h1; k = c*9+tap (plain weight layout)
__global__ __launch_bounds__(256) void build_GA(
    const float* __restrict__ h1, ushort* __restrict__ GA)
{
  int i = blockIdx.x * 256 + threadIdx.x;
  if (i >= 72 * 2304) return;
  int row = i / 2304, k = i - row * 2304;
  int c = k / 9, tap = k - c * 9;
  int u = row % 9;
  int ty = u / 3, tx = u - ty * 3;
  int dy = tap / 3, dx = tap - dy * 3;
  int uy = (ty == 0) ? (dy == 0 ? 0 : 1) : (ty == 2) ? (dy == 2 ? 2 : 1) : 1;
  int ux = (tx == 0) ? (dx == 0 ? 0 : 1) : (tx == 2) ? (dx == 2 ? 2 : 1) : 1;
  GA[i] = f2h(h1[(row / 9) * 2304 + c * 9 + uy * 3 + ux]);
}

// softmax over 1444 fp16 logits (row stride 1472) -> fp16 rows (1472, padded)
// R22: vectorized h8 load/store, register-resident, masked 1444-tail.
__global__ __launch_bounds__(256) void softmax_h16(
    const ushort* __restrict__ p, ushort* __restrict__ wt)
{
  long row = blockIdx.x;
  const ushort* rp = p + row * 1472;
  ushort* op = wt + row * 1472;
  int t = threadIdx.x;
  __shared__ float redm[4], reds[4];
  float v[8];
  const bool act = t < 184;            // 184*8 = 1472
  const int base = t * 8;
  float mx = -3.4e38f;
  if (act) {
    h8 hv = *(const h8*)(const void*)(rp + base);
    #pragma unroll
    for (int j = 0; j < 8; ++j) {
      v[j] = (base + j < 1444) ? (float)hv[j] : -3.4e38f;
      mx = fmaxf(mx, v[j]);
    }
  }
  #pragma unroll
  for (int o = 32; o; o >>= 1) mx = fmaxf(mx, __shfl_down(mx, o));
  if ((t & 63) == 0) redm[t >> 6] = mx;
  __syncthreads();
  mx = fmaxf(fmaxf(redm[0], redm[1]), fmaxf(redm[2], redm[3]));
  float s = 0.f;
  if (act) {
    #pragma unroll
    for (int j = 0; j < 8; ++j) {
      float e = (base + j < 1444) ? expf(v[j] - mx) : 0.f;
      v[j] = e; s += e;
    }
  }
  #pragma unroll
  for (int o = 32; o; o >>= 1) s += __shfl_down(s, o);
  if ((t & 63) == 0) reds[t >> 6] = s;
  __syncthreads();
  float inv = 1.f / (reds[0] + reds[1] + reds[2] + reds[3]);
  if (act) {
    h8 hw;
    #pragma unroll
    for (int j = 0; j < 8; ++j) hw[j] = (f16)(v[j] * inv);
    *(h8*)(void*)(op + base) = hw;
  }
}

// step-2 (a=0,b=1) classed attention; sums 6 khvc K-slice partials
__global__ __launch_bounds__(256) void attn_b1(
    const ushort* __restrict__ qT, const float* __restrict__ khvcp,
    ushort* __restrict__ xaT)
{
  __shared__ float ks[2304];   // [tt*256 + c]
  __shared__ float vs[2304];
  __shared__ float es[256][10];
  int n = blockIdx.y;
  int q0 = blockIdx.x * 256;
  for (int i = threadIdx.x; i < 2304; i += 256) {
    int tt = i >> 8, c = i & 255;
    size_t base = (size_t)(n * 9 + tt) * 512;
    float sk = 0.f, sv = 0.f;
    #pragma unroll
    for (int s = 0; s < 6; ++s) {
      sk += khvcp[s * 36864 + base + c];
      sv += khvcp[s * 36864 + base + 256 + c];
    }
    ks[i] = sk; vs[i] = sv;
  }
  __syncthreads();
  int q = q0 + threadIdx.x;
  bool act = (q < 1600);
  float Lg[9] = {0.f,0.f,0.f,0.f,0.f,0.f,0.f,0.f,0.f};
  const ushort* qp = qT + (size_t)n * 409600 + (act ? (size_t)q * 256 : 0);
  for (int c8 = 0; c8 < 256; c8 += 8) {
    h8 v = *(const h8*)(const void*)(qp + c8);
    #pragma unroll
    for (int j = 0; j < 8; ++j) {
      float f = (float)v[j];
      #pragma unroll
      for (int tt = 0; tt < 9; ++tt) Lg[tt] += f * ks[tt * 256 + c8 + j];
    }
  }
  float mx = Lg[0];
  #pragma unroll
  for (int tt = 1; tt < 9; ++tt) mx = fmaxf(mx, Lg[tt]);
  float Z = 0.f;
  float e[9];
  #pragma unroll
  for (int tt = 0; tt < 9; ++tt) {
    float m = ((tt / 3) == 1 ? 36.f : 1.f) * ((tt % 3) == 1 ? 36.f : 1.f);
    e[tt] = act ? m * expf(Lg[tt] - mx) : 0.f;
    Z += e[tt];
  }
  float inv = act ? (1.f / Z) : 0.f;
  #pragma unroll
  for (int tt = 0; tt < 9; ++tt) es[threadIdx.x][tt] = e[tt] * inv;
  __syncthreads();
  int nact = 1600 - q0; if (nact > 256) nact = 256;
  int p = threadIdx.x;
  for (int qq = 0; qq < nact; ++qq) {
    float s = 0.f;
    #pragma unroll
    for (int tt = 0; tt < 9; ++tt) s += es[qq][tt] * vs[tt * 256 + p];
    xaT[(size_t)n * 1228800 + (size_t)(q0 + qq) * 768 + 512 + p] = f2h(s);
  }
}

// ---------------------------------------------------------------------------
extern "C" void kernel_launch(void* const* d_in, const int* in_sizes, int n_in,
                              void* d_out, int out_size, void* d_ws, size_t ws_size,
                              hipStream_t stream)
{
  const float* x     = (const float*)d_in[0];
  const float* h0    = (const float*)d_in[1];
  const float* w_px  = (const float*)d_in[2];
  const float* b_px  = (const float*)d_in[3];
  const float* w_qx  = (const float*)d_in[4];
  const float* w_qh  = (const float*)d_in[5];
  const float* w_kx  = (const float*)d_in[6];
  const float* w_kh  = (const float*)d_in[7];
  const float* w_vx  = (const float*)d_in[8];
  const float* w_vh  = (const float*)d_in[9];
  const float* w_z   = (const float*)d_in[10];
  const float* b_z   = (const float*)d_in[11];
  const float* w_h   = (const float*)d_in[12];
  const float* b_h   = (const float*)d_in[13];
  const float* w_out = (const float*)d_in[14];
  const float* b_out = (const float*)d_in[15];
  float* out = (float*)d_out;

  char* base = (char*)d_ws;
  size_t off = 0;
  auto alloc = [&](size_t bytes) -> char* {
    off = (off + 255) & ~(size_t)255;
    char* p = base + off; off += bytes; return p;
  };
  ushort* xaT   = (ushort*)alloc(19660800);         // [8][1600][768] fp16
  ushort* qT    = (ushort*)alloc(6553600);          // [8][1600][256]
  ushort* kxT   = (ushort*)alloc(5914624);          // [8][1444][256]
  ushort* vxp   = (ushort*)alloc(6029312);          // [8][256][1472]
  ushort* xT    = (ushort*)alloc(3276800);          // [12800][128]
  ushort* Wqk   = (ushort*)alloc(2359296);          // [512][2304] conv-K order
  ushort* Wv    = (ushort*)alloc(1179648);          // [256][2304] conv-K order
  ushort* Wkv   = (ushort*)alloc(2359296);          // [512][2304]: w_kh|w_vh
  ushort* Wzh   = (ushort*)alloc(524288);           // [512][512]: w_z|w_h
  ushort* wpx   = (ushort*)alloc(65536);            // [256][128]
  ushort* wout  = (ushort*)alloc(393216);           // [256][768]
  ushort* zp    = (ushort*)alloc(128);              // 64-ushort zero page
  ushort* GA    = (ushort*)alloc(331776);           // [72][2304] fp16
  ushort* AV    = (ushort*)alloc(73728);            // [72][512] fp16
  float*  pre72p= (float*)alloc(589824);            // [4][72][512] partials
  float*  khvcp = (float*)alloc(884736);            // [6][72][512] partials
  float*  qh1   = (float*)alloc(9216);
  float*  kh1   = (float*)alloc(1024);
  float*  vh1   = (float*)alloc(1024);
  float*  L0    = (float*)alloc(415872);            // [8][9][1444] raw logits
  float*  h1    = (float*)alloc(73728);
  off = (off + 255) & ~(size_t)255;
  char* chunk = base + off;
  long avail = (long)ws_size - (long)off;
  if (avail < 0) avail = 0;
  int an = (int)(avail / 9420800L); if (an < 1) an = 1; if (an > 8) an = 8;

  auto mk = [&](const ushort* A, long sAb, const ushort* B, long sBb,
                int M, int Nn, int K, int Krow, int mode, int gRow0, int swap,
                int aConv, int bConv,
                float* Y, long sYb, long sYm, int nPer, long sYb2,
                const float* bias, int biasN,
                ushort* Yh, long sYpb, long sYpm, long pOff, ushort* Y2h) {
    MgArgs g;
    g.A = A; g.sAb = sAb; g.B = B; g.sBb = sBb;
    g.M = M; g.Nn = Nn; g.K = K; g.Krow = Krow; g.mode = mode;
    g.gRow0 = gRow0; g.swap = swap; g.aConv = aConv; g.bConv = bConv;
    g.zp = zp;
    g.Y = Y; g.sYb = sYb; g.sYm = sYm; g.nPer = nPer; g.sYb2 = sYb2;
    g.bias = bias; g.biasN = biasN;
    g.Yh = Yh; g.sYpb = sYpb; g.sYpm = sYpm; g.pOff = pOff; g.Y2h = Y2h;
    return g;
  };
  const int BIG = 0x40000000;

  // ---- 1) prep: xT transpose (LDS-tiled) + fused weight conversions ----
  xt_kern<<<dim3(25, 8), dim3(256), 0, stream>>>(x, xT);
  prep_all<<<dim3(13664), dim3(256), 0, stream>>>(
      w_qx, w_kx, w_vx, w_px, w_out, w_kh, w_vh, w_z, w_h,
      Wqk, Wv, wpx, wout, Wkv, Wzh, zp, vxp);

  // ---- 2) xp-conv: A=xT[12800][128], B=wpx -> xaT cols 0..255 ----
  mg_xp<<<dim3(4, 200, 1), dim3(256), 0, stream>>>(mk(xT, 0, wpx, 0,
     12800, 256, 128, 128, 1, 0, 1, 0, 0,
     nullptr, 0, 0, 0, 0, b_px, 1,
     xaT, 0, 768, 0, nullptr));

  // ---- 3) direct shifted-tap convs (conv-K order) ----
  // qk on the 64x128 single-buf variant (converged best, ~60.5us)
  mgemm_w<<<dim3(4, 200, 1), dim3(256), 0, stream>>>(xaT, 0, Wqk, 0,
     12800, 512, 2304, 2304, 2, 0, 1, 1, 0, zp,
     nullptr, 0, 0, 0, 0, nullptr, 0,
     qT, 0, 0, 0, kxT);
  mg_v<<<dim3(4, 200, 1), dim3(256), 0, stream>>>(mk(Wv, 0, xaT, 0,
     256, 12800, 2304, 2304, 3, 0, 0, 0, 1,
     nullptr, 0, 0, 0, 0, nullptr, 0,
     vxp, 0, 0, 0, nullptr));

  // ---- 4) classed section (fused chain, R21) ----
  uniform_kv_kern<<<dim3(256, 11), dim3(64), 0, stream>>>(h0, w_qh, w_kh, w_vh, qh1, kh1, vh1);
  l0_logits<<<dim3(6, 8), dim3(256), 0, stream>>>(qh1, kxT, L0);
  a10_pv_av<<<dim3(9, 8), dim3(256), 0, stream>>>(L0, vxp, vh1, AV);
  // AV[72][512] x Wzh[512][512], 4 K-slices of 128 -> pre72p[4][72][512]
  mg_cls<<<dim3(2, 8, 4), dim3(256), 0, stream>>>(mk(AV, 128, Wzh, 128,
     72, 512, 128, 512, 0, 0, 0, 0, 0,
     pre72p, 36864, 512, BIG, 0, nullptr, 0,
     nullptr, 0, 0, 0, nullptr));
  gate_ew2<<<dim3(72), dim3(256), 0, stream>>>(pre72p, b_z, b_h, h0, h1);
  build_GA<<<dim3(648), dim3(256), 0, stream>>>(h1, GA);
  // GA[72][2304] x Wkv[512][2304], 6 K-slices of 384 -> khvcp[6][72][512]
  mg_cls<<<dim3(2, 8, 6), dim3(256), 0, stream>>>(mk(GA, 384, Wkv, 384,
     72, 512, 384, 2304, 0, 0, 0, 0, 0,
     khvcp, 36864, 512, BIG, 0, nullptr, 0,
     nullptr, 0, 0, 0, nullptr));
  attn_b1<<<dim3(7, 8), dim3(256), 0, stream>>>(qT, khvcp, xaT);

  // ---- 5) step-2 (0,0) full attention (fp16 logits) ----
  {
    ushort* scL16 = (ushort*)chunk;
    for (int nb0 = 0; nb0 < 8; nb0 += an) {
      int c = (8 - nb0 < an) ? (8 - nb0) : an;
      ushort* wt = (ushort*)(chunk + (long)c * 4710400);
      mg_lg<<<dim3(25, 23, c), dim3(256), 0, stream>>>(mk(qT + (long)nb0 * 409600, 409600,
         kxT + (long)nb0 * 369664, 369664,
         1600, 1444, 256, 256, 1, 0, 0, 0, 0,
         nullptr, 0, 0, 0, 0, nullptr, 0,
         scL16, 2355200, 1472, 0, nullptr));
      softmax_h16<<<dim3(c * 1600), dim3(256), 0, stream>>>(scL16, wt);
      mg_pv<<<dim3(25, 4, c), dim3(256), 0, stream>>>(mk(wt, 2355200,
         vxp + (long)nb0 * 376832, 376832,
         1600, 256, 1472, 1472, 1, 0, 0, 0, 0,
         nullptr, 0, 0, 0, 0, nullptr, 0,
         xaT + (long)nb0 * 1228800, 1228800, 768, 256, nullptr));
    }
  }

  // ---- 6) out-conv: A=wout[256][768], B=xaT rows -> fp32 NCHW ----
  mg_out<<<dim3(4, 200, 1), dim3(256), 0, stream>>>(mk(wout, 0, xaT, 0,
     256, 12800, 768, 768, 0, 0, 0, 0, 0,
     out, 0, 1600, 1600, 409600, b_out, 0,
     nullptr, 0, 0, 0, nullptr));
}

// Round 13
// 445.353 us; speedup vs baseline: 1.1232x; 1.1232x over previous
//
#include <hip/hip_runtime.h>
#include <math.h>

// ---------------------------------------------------------------------------
// 2-step recurrent attention cell, N=8, I=128, C=Hc=A=P=O=256, H=W=40
// (Q=1600), VALID 3x3 -> 38x38 (D=1444). fp32 reference.
//
// R0-R10: algebraic reductions, MFMA GEMMs, DMA staging + XOR swizzle,
// direct shifted-tap conv, fp16 single-plane, 72-row classed GEMMs.
// R11-R13 FAILED (journal). R14 WIN (529->460): 64x128 tile.
// R15/R16 FAILED: BK=128 / dbuf@48KB (occupancy loss dominates).
// R17 WIN (460->442): 64x64+static dbuf @32KB. R18: qk on 64x128 single-buf.
// R19 WIN (->436.6): counted-vmcnt T4 on 64x64 dbuf + named wrappers.
// R20 FAILED-BRANCH: qk dbuf@48KB (occupancy). qk CONVERGED ~60us (R14 geom).
// R21 NEUTRAL (437.2): classed-chain fusion (kept: fewer kernels, same perf).
// R22 CONFOUNDED (500): untouched mgemm_w slowed 59.6->92us with identical
// counters except memory rate (682->442 GB/s) -- control kernel moved, so
// the measurement is invalid (machine variance or unknown global effect).
// R23: clean revert to R21 source to re-anchor. Pre-committed read:
// total~437 -> baseline restored, re-introduce R22 pieces singly;
// total~500 -> machine re-baselined, continue against new floor.
// ---------------------------------------------------------------------------

typedef _Float16 f16;
typedef _Float16 h8 __attribute__((ext_vector_type(8)));   // 8 fp16 (4 VGPRs)
typedef __attribute__((ext_vector_type(4))) float f4;

__device__ __forceinline__ ushort f2h(float f) {
  union { f16 h; ushort u; } cv; cv.h = (f16)f; return cv.u;
}
__device__ __forceinline__ float h2f(ushort u) {
  union { ushort u; f16 h; } cv; cv.u = u; return (float)cv.h;
}

// ---------------- MFMA fp16 GEMM, 64x64 tile, counted-vmcnt dbuf -----------
// (R19 structure, unchanged.) C[m][n] = sum_k A[m][k]*B[n][k].
struct MgArgs {
  const ushort* A; long sAb;
  const ushort* B; long sBb;
  int M, Nn, K, Krow, mode, gRow0, swap, aConv, bConv;
  const ushort* zp;
  float* Y; long sYb, sYm; int nPer; long sYb2;
  const float* bias; int biasN;
  ushort* Yh; long sYpb, sYpm, pOff;
  ushort* Y2h;
};

__device__ __forceinline__ void mg_body(const MgArgs& g, ushort* lbase)
{
  const int bz = blockIdx.z;
  const ushort* __restrict__ A = g.A + (long)bz * g.sAb;
  const ushort* __restrict__ B = g.B + (long)bz * g.sBb;
  const int mb = g.swap ? blockIdx.y : blockIdx.x;
  const int nb = g.swap ? blockIdx.x : blockIdx.y;
  const int m0 = mb * 64, n0 = nb * 64;
  const int t = threadIdx.x;
  const int lane = t & 63, wv = t >> 6;
  const int r = lane & 15, qd = lane >> 4;
  const int wn = wv * 16;
  const int lrow = lane >> 3, lch = lane & 7;
  f4 acc[4];
  #pragma unroll
  for (int i = 0; i < 4; ++i) acc[i] = (f4){0.f, 0.f, 0.f, 0.f};

  const int cg8 = (lch ^ lrow) * 8;
  int aB[2], aY[2], aX[2]; long aO[2];
  int bB[2], bY[2], bX[2]; long bO[2];
  #pragma unroll
  for (int i = 0; i < 2; ++i) {        // A rows: wv*16 + i*8 + lrow (0..63)
    int gr = m0 + wv * 16 + i * 8 + lrow;
    if (g.aConv) {
      int n8 = gr / 1600, pos = gr - n8 * 1600;
      int py = pos / 40, px = pos - py * 40;
      aB[i] = n8 * 1600; aY[i] = py; aX[i] = px;
    } else { if (gr > g.M - 1) gr = g.M - 1; aO[i] = (long)gr * g.Krow; }
  }
  #pragma unroll
  for (int i = 0; i < 2; ++i) {        // B rows: wv*16 + i*8 + lrow (0..63)
    int gr = n0 + wv * 16 + i * 8 + lrow;
    if (g.bConv) {
      int n8 = gr / 1600, pos = gr - n8 * 1600;
      int py = pos / 40, px = pos - py * 40;
      bB[i] = n8 * 1600; bY[i] = py; bX[i] = px;
    } else { if (gr > g.Nn - 1) gr = g.Nn - 1; bO[i] = (long)gr * g.Krow; }
  }

  auto stage = [&](int ch, int lb) {
    int cb = ch / 9, tap = ch - cb * 9;       // conv-K: cb-major, tap-minor
    int tdy = tap / 3 - 1, tdx = tap - (tap / 3) * 3 - 1;
    int kin = cb << 6;
    int kc2 = ch << 6;
    #pragma unroll
    for (int i = 0; i < 2; ++i) {             // A (2 x 16B per thread)
      const ushort* p; size_t go;
      if (g.aConv) {
        int yy = aY[i] + tdy, xx = aX[i] + tdx;
        bool v = ((unsigned)yy < 40u) && ((unsigned)xx < 40u);
        if (v) { go = (size_t)(aB[i] + yy * 40 + xx) * 768 + kin + cg8; p = A; }
        else   { go = 0; p = g.zp; }
      } else { go = (size_t)(aO[i] + kc2 + cg8); p = A; }
      __builtin_amdgcn_global_load_lds(p + go, lbase + lb + wv * 1024 + i * 512, 16, 0, 0);
    }
    #pragma unroll
    for (int i = 0; i < 2; ++i) {             // B (2 x 16B per thread)
      const ushort* p; size_t go;
      if (g.bConv) {
        int yy = bY[i] + tdy, xx = bX[i] + tdx;
        bool v = ((unsigned)yy < 40u) && ((unsigned)xx < 40u);
        if (v) { go = (size_t)(bB[i] + yy * 40 + xx) * 768 + kin + cg8; p = B; }
        else   { go = 0; p = g.zp; }
      } else { go = (size_t)(bO[i] + kc2 + cg8); p = B; }
      __builtin_amdgcn_global_load_lds(p + go, lbase + lb + 4096 + wv * 1024 + i * 512, 16, 0, 0);
    }
  };

  auto compute = [&](int lb) {
    #pragma unroll
    for (int kk = 0; kk < 2; ++kk) {
      int off = (((kk << 2) + qd) ^ (r & 7)) << 3;
      h8 af[4], bf;
      #pragma unroll
      for (int mt = 0; mt < 4; ++mt)
        af[mt] = *(const h8*)&lbase[lb + (mt * 16 + r) * 64 + off];
      bf = *(const h8*)&lbase[lb + 4096 + (wn + r) * 64 + off];
      #pragma unroll
      for (int mt = 0; mt < 4; ++mt)
        acc[mt] = __builtin_amdgcn_mfma_f32_16x16x32_f16(af[mt], bf, acc[mt], 0, 0, 0);
    }
  };

  // counted-vmcnt 2-phase (T4): never drain vmcnt to 0 mid-loop.
  const int nch = g.K >> 6;
  stage(0, 0);                                  // out: ch0(4)
  int ch = 0;
  while (ch + 2 <= nch) {
    stage(ch + 1, 8192);                        // out: ch(4)+ch1(4)
    asm volatile("s_waitcnt vmcnt(4)" ::: "memory");   // ch landed
    __builtin_amdgcn_s_barrier();
    __builtin_amdgcn_sched_barrier(0);
    compute(0);
    __builtin_amdgcn_s_barrier();               // WAR: reads of b0 done
    __builtin_amdgcn_sched_barrier(0);
    if (ch + 2 < nch) {
      stage(ch + 2, 0);                         // out: ch1(<=4)+ch2(4)
      asm volatile("s_waitcnt vmcnt(4)" ::: "memory"); // ch+1 landed
    } else {
      asm volatile("s_waitcnt vmcnt(0)" ::: "memory"); // no new loads issued
    }
    __builtin_amdgcn_s_barrier();
    __builtin_amdgcn_sched_barrier(0);
    compute(8192);
    __builtin_amdgcn_s_barrier();               // WAR: reads of b1 done
    __builtin_amdgcn_sched_barrier(0);
    ch += 2;
  }
  if (ch < nch) {                               // odd tail (staged into b0)
    asm volatile("s_waitcnt vmcnt(0)" ::: "memory");
    __builtin_amdgcn_s_barrier();
    __builtin_amdgcn_sched_barrier(0);
    compute(0);
  }

  #pragma unroll
  for (int mt = 0; mt < 4; ++mt) {
    int nn = n0 + wn + r;
    if (nn >= g.Nn) continue;
    #pragma unroll
    for (int e = 0; e < 4; ++e) {
      int mm = m0 + mt * 16 + qd * 4 + e;
      if (mm >= g.M) continue;
      float v = acc[mt][e];
      if (g.mode == 0) {
        if (g.bias) v += g.bias[mm];
        int b2 = nn / g.nPer, nq = nn - b2 * g.nPer;
        g.Y[(size_t)bz * g.sYb + (size_t)b2 * g.sYb2 + (size_t)mm * g.sYm + nq] = v;
      } else if (g.mode == 1) {
        if (g.bias) v += g.bias[g.biasN ? nn : mm];
        g.Yh[(size_t)bz * g.sYpb + (size_t)mm * g.sYpm + nn + g.pOff] = f2h(v);
      } else if (g.mode == 2) {
        int gm = g.gRow0 + mm;
        int n8 = gm / 1600, q = gm - n8 * 1600;
        ushort h = f2h(v);
        if (nn < 256) {
          g.Yh[(size_t)n8 * 409600 + (size_t)q * 256 + nn] = h;
        } else {
          int qy = q / 40, qx = q - qy * 40;
          if (qy >= 1 && qy <= 38 && qx >= 1 && qx <= 38)
            g.Y2h[(size_t)n8 * 369664 + (size_t)((qy - 1) * 38 + qx - 1) * 256 + (nn - 256)] = h;
        }
      } else {   // mode 3
        int gn = g.gRow0 + nn;
        int n8 = gn / 1600, q = gn - n8 * 1600;
        int qy = q / 40, qx = q - qy * 40;
        if (qy >= 1 && qy <= 38 && qx >= 1 && qx <= 38)
          g.Yh[(size_t)n8 * 376832 + (size_t)mm * 1472 + (qy - 1) * 38 + qx - 1] = f2h(v);
      }
    }
  }
}

// named wrappers: one per call site for rocprof attribution
#define MG_KERN(name) \
__global__ __launch_bounds__(256) void name(MgArgs g) { \
  __shared__ ushort S[16384]; mg_body(g, S); }
MG_KERN(mg_xp)
MG_KERN(mg_v)
MG_KERN(mg_cls)
MG_KERN(mg_lg)
MG_KERN(mg_pv)
MG_KERN(mg_out)
#undef MG_KERN

// ---------------- MFMA fp16 GEMM, 64x128 tile, single-buf (R14) ------------
// qk-conv only. CONVERGED at ~60.5us across 6 tested structures: occupancy
// (24KB LDS, ~2.7 blocks/CU) beats every pipelining variant on this shape.
__global__ __launch_bounds__(256) void mgemm_w(
    const ushort* __restrict__ A, long sAb,
    const ushort* __restrict__ B, long sBb,
    int M, int Nn, int K, int Krow, int mode, int gRow0, int swap,
    int aConv, int bConv,
    const ushort* __restrict__ zp,
    float* __restrict__ Y, long sYb, long sYm, int nPer, long sYb2,
    const float* __restrict__ bias, int biasN,
    ushort* __restrict__ Yh, long sYpb, long sYpm, long pOff,
    ushort* __restrict__ Y2h)
{
  __shared__ ushort S[12288];   // SA[64][64] @ 0, SB[128][64] @ 4096 ; 24 KB
  const int bz = blockIdx.z;
  A += (long)bz * sAb;
  B += (long)bz * sBb;
  const int mb = swap ? blockIdx.y : blockIdx.x;
  const int nb = swap ? blockIdx.x : blockIdx.y;
  const int m0 = mb * 64, n0 = nb * 128;
  const int t = threadIdx.x;
  const int lane = t & 63, wv = t >> 6;
  const int r = lane & 15, qd = lane >> 4;
  const int wn = wv * 32;
  const int lrow = lane >> 3, lch = lane & 7;
  f4 acc[4][2];
  #pragma unroll
  for (int i = 0; i < 4; ++i)
    #pragma unroll
    for (int j = 0; j < 2; ++j) acc[i][j] = (f4){0.f, 0.f, 0.f, 0.f};

  const int cg8 = (lch ^ lrow) * 8;
  int aB[2], aY[2], aX[2]; long aO[2];
  int bB[4], bY[4], bX[4]; long bO[4];
  #pragma unroll
  for (int i = 0; i < 2; ++i) {        // A rows: wv*16 + i*8 + lrow (0..63)
    int gr = m0 + wv * 16 + i * 8 + lrow;
    if (aConv) {
      int n8 = gr / 1600, pos = gr - n8 * 1600;
      int py = pos / 40, px = pos - py * 40;
      aB[i] = n8 * 1600; aY[i] = py; aX[i] = px;
    } else { if (gr > M - 1) gr = M - 1; aO[i] = (long)gr * Krow; }
  }
  #pragma unroll
  for (int i = 0; i < 4; ++i) {        // B rows: wv*32 + i*8 + lrow (0..127)
    int gr = n0 + wv * 32 + i * 8 + lrow;
    if (bConv) {
      int n8 = gr / 1600, pos = gr - n8 * 1600;
      int py = pos / 40, px = pos - py * 40;
      bB[i] = n8 * 1600; bY[i] = py; bX[i] = px;
    } else { if (gr > Nn - 1) gr = Nn - 1; bO[i] = (long)gr * Krow; }
  }

  ushort* lbase = S;
  for (int kc = 0; kc < K; kc += 64) {
    __syncthreads();
    int ch = kc >> 6;
    int cb = ch / 9, tap = ch - cb * 9;       // conv-K: cb-major, tap-minor
    int tdy = tap / 3 - 1, tdx = tap - (tap / 3) * 3 - 1;
    int kin = cb << 6;
    #pragma unroll
    for (int i = 0; i < 2; ++i) {             // stage A (2 x 16B per thread)
      const ushort* p; size_t go;
      if (aConv) {
        int yy = aY[i] + tdy, xx = aX[i] + tdx;
        bool v = ((unsigned)yy < 40u) && ((unsigned)xx < 40u);
        if (v) { go = (size_t)(aB[i] + yy * 40 + xx) * 768 + kin + cg8; p = A; }
        else   { go = 0; p = zp; }
      } else { go = (size_t)(aO[i] + kc + cg8); p = A; }
      __builtin_amdgcn_global_load_lds(p + go, lbase + wv * 1024 + i * 512, 16, 0, 0);
    }
    #pragma unroll
    for (int i = 0; i < 4; ++i) {             // stage B (4 x 16B per thread)
      const ushort* p; size_t go;
      if (bConv) {
        int yy = bY[i] + tdy, xx = bX[i] + tdx;
        bool v = ((unsigned)yy < 40u) && ((unsigned)xx < 40u);
        if (v) { go = (size_t)(bB[i] + yy * 40 + xx) * 768 + kin + cg8; p = B; }
        else   { go = 0; p = zp; }
      } else { go = (size_t)(bO[i] + kc + cg8); p = B; }
      __builtin_amdgcn_global_load_lds(p + go, lbase + 4096 + wv * 2048 + i * 512, 16, 0, 0);
    }
    __syncthreads();
    #pragma unroll
    for (int kk = 0; kk < 2; ++kk) {
      int off = (((kk << 2) + qd) ^ (r & 7)) << 3;
      h8 af[4], bf[2];
      #pragma unroll
      for (int mt = 0; mt < 4; ++mt)
        af[mt] = *(const h8*)&lbase[(mt * 16 + r) * 64 + off];
      #pragma unroll
      for (int nt = 0; nt < 2; ++nt)
        bf[nt] = *(const h8*)&lbase[4096 + (wn + nt * 16 + r) * 64 + off];
      #pragma unroll
      for (int mt = 0; mt < 4; ++mt)
        #pragma unroll
        for (int nt = 0; nt < 2; ++nt)
          acc[mt][nt] = __builtin_amdgcn_mfma_f32_16x16x32_f16(af[mt], bf[nt], acc[mt][nt], 0, 0, 0);
    }
  }
  #pragma unroll
  for (int mt = 0; mt < 4; ++mt)
    #pragma unroll
    for (int nt = 0; nt < 2; ++nt) {
      int nn = n0 + wn + nt * 16 + r;
      if (nn >= Nn) continue;
      #pragma unroll
      for (int e = 0; e < 4; ++e) {
        int mm = m0 + mt * 16 + qd * 4 + e;
        if (mm >= M) continue;
        float v = acc[mt][nt][e];
        if (mode == 0) {
          if (bias) v += bias[mm];
          int b2 = nn / nPer, nq = nn - b2 * nPer;
          Y[(size_t)bz * sYb + (size_t)b2 * sYb2 + (size_t)mm * sYm + nq] = v;
        } else if (mode == 1) {
          if (bias) v += bias[biasN ? nn : mm];
          Yh[(size_t)bz * sYpb + (size_t)mm * sYpm + nn + pOff] = f2h(v);
        } else if (mode == 2) {
          int gm = gRow0 + mm;
          int n8 = gm / 1600, q = gm - n8 * 1600;
          ushort h = f2h(v);
          if (nn < 256) {
            Yh[(size_t)n8 * 409600 + (size_t)q * 256 + nn] = h;
          } else {
            int qy = q / 40, qx = q - qy * 40;
            if (qy >= 1 && qy <= 38 && qx >= 1 && qx <= 38)
              Y2h[(size_t)n8 * 369664 + (size_t)((qy - 1) * 38 + qx - 1) * 256 + (nn - 256)] = h;
          }
        } else {   // mode 3
          int gn = gRow0 + nn;
          int n8 = gn / 1600, q = gn - n8 * 1600;
          int qy = q / 40, qx = q - qy * 40;
          if (qy >= 1 && qy <= 38 && qx >= 1 && qx <= 38)
            Yh[(size_t)n8 * 376832 + (size_t)mm * 1472 + (qy - 1) * 38 + qx - 1] = f2h(v);
        }
      }
    }
}

// ---------------- fused prep: all weight/input conversions + pads ----------
// range-dispatched single kernel (replaces 8 small launches)
__global__ __launch_bounds__(256) void prep_all(
    const float* __restrict__ x,
    const float* __restrict__ w_qx, const float* __restrict__ w_kx,
    const float* __restrict__ w_vx,
    const float* __restrict__ w_px, const float* __restrict__ w_out,
    const float* __restrict__ w_kh, const float* __restrict__ w_vh,
    const float* __restrict__ w_z, const float* __restrict__ w_h,
    ushort* __restrict__ xT, ushort* __restrict__ Wqk, ushort* __restrict__ Wv,
    ushort* __restrict__ wpx, ushort* __restrict__ wout,
    ushort* __restrict__ Wkv, ushort* __restrict__ Wzh,
    ushort* __restrict__ zp, ushort* __restrict__ vxp)
{
  long gi = (long)blockIdx.x * 256 + threadIdx.x;
  if (gi < 64) zp[gi] = 0;
  long i = gi;
  if (i < 1638400) {                         // xT [12800][128] transpose-cvt
    int i1 = (int)(i & 127); long r = i >> 7;
    int q = (int)(r % 1600); int n8 = (int)(r / 1600);
    xT[i] = f2h(x[(long)n8 * 204800 + (long)i1 * 1600 + q]);
    return;
  }
  i -= 1638400;
  if (i < 1769472) {                         // Wqk/Wv conv-K reorder
    int o = (int)(i / 2304), k = (int)(i - (long)o * 2304);
    int cb = k / 576, rem = k - cb * 576;
    int tap = rem >> 6, ci = rem & 63;
    int si = (cb * 64 + ci) * 9 + tap;
    float f; ushort* d; int oo;
    if (o < 256)      { f = w_qx[o * 2304 + si];         d = Wqk; oo = o; }
    else if (o < 512) { f = w_kx[(o - 256) * 2304 + si]; d = Wqk; oo = o; }
    else              { f = w_vx[(o - 512) * 2304 + si]; d = Wv;  oo = o - 512; }
    d[oo * 2304 + k] = f2h(f);
    return;
  }
  i -= 1769472;
  if (i < 32768)  { wpx[i]  = f2h(w_px[i]);  return; }
  i -= 32768;
  if (i < 196608) { wout[i] = f2h(w_out[i]); return; }
  i -= 196608;
  if (i < 1179648) { Wkv[i] = f2h(i < 589824 ? w_kh[i] : w_vh[i - 589824]); return; }
  i -= 1179648;
  if (i < 262144)  { Wzh[i] = f2h(i < 131072 ? w_z[i] : w_h[i - 131072]); return; }
  i -= 262144;
  if (i < 57344) {                           // vxp pad cols 1444..1471
    int j = (int)(i % 28); int rr = (int)(i / 28);
    int c = rr % 256, n = rr / 256;
    vxp[(size_t)n * 376832 + (size_t)c * 1472 + 1444 + j] = 0;
  }
}

// step-1 uniform-h class tables
__global__ __launch_bounds__(64) void uniform_kv_kern(
    const float* __restrict__ h0, const float* __restrict__ w_qh,
    const float* __restrict__ w_kh, const float* __restrict__ w_vh,
    float* __restrict__ qh1, float* __restrict__ kh1, float* __restrict__ vh1)
{
  int a = blockIdx.x, j = blockIdx.y, t = threadIdx.x;
  const float* wsel = (j < 9) ? w_qh : (j == 9) ? w_kh : w_vh;
  bool dyok0 = true, dyok2 = true, dxok0 = true, dxok2 = true;
  if (j < 9) {
    int uy = j / 3, ux = j - uy * 3;
    dyok0 = (uy != 0); dyok2 = (uy != 2);
    dxok0 = (ux != 0); dxok2 = (ux != 2);
  }
  float acc = 0.f;
  for (int c = t; c < 256; c += 64) {
    const float* wp = wsel + a * 2304 + c * 9;
    float s = 0.f;
    #pragma unroll
    for (int dy = 0; dy < 3; ++dy) {
      if ((dy == 0 && !dyok0) || (dy == 2 && !dyok2)) continue;
      #pragma unroll
      for (int dx = 0; dx < 3; ++dx) {
        if ((dx == 0 && !dxok0) || (dx == 2 && !dxok2)) continue;
        s += wp[dy * 3 + dx];
      }
    }
    acc += s * h0[c];
  }
  #pragma unroll
  for (int o = 32; o; o >>= 1) acc += __shfl_down(acc, o);
  if (t == 0) {
    if (j < 9) qh1[j * 256 + a] = acc;
    else if (j == 9) kh1[a] = acc;
    else vh1[a] = acc;
  }
}

// L0[n][u][d] = sum_c qh1[u][c] * k_x[n][d][c]  (kxT fp16) -- raw logits
__global__ __launch_bounds__(256) void l0_logits(
    const float* __restrict__ qh1, const ushort* __restrict__ kxT,
    float* __restrict__ L0)
{
  __shared__ float qs[2304];
  int db = blockIdx.x, n = blockIdx.y;
  for (int i = threadIdx.x; i < 2304; i += 256) qs[i] = qh1[i];
  __syncthreads();
  int d = db * 256 + threadIdx.x;
  bool act = d < 1444;
  const ushort* vp = kxT + (size_t)n * 369664 + (act ? (size_t)d * 256 : 0);
  float acc[9] = {0.f,0.f,0.f,0.f,0.f,0.f,0.f,0.f,0.f};
  for (int c8 = 0; c8 < 256; c8 += 8) {
    h8 v = *(const h8*)(const void*)(vp + c8);
    #pragma unroll
    for (int j = 0; j < 8; ++j) {
      float f = (float)v[j];
      #pragma unroll
      for (int u = 0; u < 9; ++u) acc[u] += qs[u * 256 + c8 + j] * f;
    }
  }
  if (act)
    for (int u = 0; u < 9; ++u) L0[n * 12996 + u * 1444 + d] = acc[u];
}

// FUSED (R21): row-softmax over raw L0[n][u][:1444] + PV vs vxp + AV write.
__global__ __launch_bounds__(256) void a10_pv_av(
    const float* __restrict__ L0, const ushort* __restrict__ vxp,
    const float* __restrict__ vh1, ushort* __restrict__ AV)
{
  int u = blockIdx.x, n = blockIdx.y;
  __shared__ float wts[1472];
  __shared__ float redm[4], reds[4];
  const float* wrow = L0 + n * 12996 + u * 1444;
  int t = threadIdx.x;
  float mx = -3.4e38f;
  for (int i = t; i < 1444; i += 256) { float v = wrow[i]; wts[i] = v; mx = fmaxf(mx, v); }
  #pragma unroll
  for (int o = 32; o; o >>= 1) mx = fmaxf(mx, __shfl_down(mx, o));
  if ((t & 63) == 0) redm[t >> 6] = mx;
  __syncthreads();
  mx = fmaxf(fmaxf(redm[0], redm[1]), fmaxf(redm[2], redm[3]));
  float s = 0.f;
  for (int i = t; i < 1444; i += 256) { float v = expf(wts[i] - mx); wts[i] = v; s += v; }
  #pragma unroll
  for (int o = 32; o; o >>= 1) s += __shfl_down(s, o);
  if ((t & 63) == 0) reds[t >> 6] = s;
  __syncthreads();
  float inv = 1.f / (reds[0] + reds[1] + reds[2] + reds[3]);
  for (int i = t; i < 1444; i += 256) wts[i] *= inv;
  if (t < 28) wts[1444 + t] = 0.f;
  __syncthreads();
  int p = t;
  const ushort* vp = vxp + (size_t)n * 376832 + (size_t)p * 1472;
  float acc = 0.f;
  for (int d8 = 0; d8 < 1472; d8 += 8) {
    h8 v = *(const h8*)(const void*)(vp + d8);
    #pragma unroll
    for (int j = 0; j < 8; ++j) acc += wts[d8 + j] * (float)v[j];
  }
  size_t row = (size_t)(n * 9 + u);
  AV[row * 512 + p] = f2h(acc);
  AV[row * 512 + 256 + p] = f2h(vh1[p]);
}

// gate tail: sum 4 K-slice partials pre72p[4][72][512], bias, GRU blend
__global__ __launch_bounds__(256) void gate_ew2(
    const float* __restrict__ pre72p, const float* __restrict__ b_z,
    const float* __restrict__ b_h, const float* __restrict__ h0,
    float* __restrict__ h1)
{
  int i = blockIdx.x * 256 + threadIdx.x;
  if (i >= 72 * 256) return;
  int row = i >> 8, c = i & 255;
  float zs = 0.f, hs = 0.f;
  #pragma unroll
  for (int s = 0; s < 4; ++s) {
    zs += pre72p[s * 36864 + row * 512 + c];
    hs += pre72p[s * 36864 + row * 512 + 256 + c];
  }
  float z = 1.f / (1.f + expf(-(zs + b_z[c])));
  float hv = tanhf(hs + b_h[c]);
  int n = row / 9, u = row - n * 9;
  h1[n * 2304 + c * 9 + u] = z * h0[c] + (1.f - z) * hv;
}

// GA[72][2304] fp16: classed im2col of h1; k = c*9+tap (plain weight layout)
__global__ __launch_bounds__(256) void build_GA(
    const float* __restrict__ h1, ushort* __restrict__ GA)
{
  int i = blockIdx.x * 256 + threadIdx.x;
  if (i >= 72 * 2304) return;
  int row = i / 2304, k = i - row * 2304;
  int c = k / 9, tap = k - c * 9;
  int u = row % 9;
  int ty = u / 3, tx = u - ty * 3;
  int dy = tap / 3, dx = tap - dy * 3;
  int uy = (ty == 0) ? (dy == 0 ? 0 : 1) : (ty == 2) ? (dy == 2 ? 2 : 1) : 1;
  int ux = (tx == 0) ? (dx == 0 ? 0 : 1) : (tx == 2) ? (dx == 2 ? 2 : 1) : 1;
  GA[i] = f2h(h1[(row / 9) * 2304 + c * 9 + uy * 3 + ux]);
}

// softmax over 1444 fp16 logits (row stride 1472) -> fp16 rows (1472, padded)
__global__ __launch_bounds__(256) void softmax_h16(
    const ushort* __restrict__ p, ushort* __restrict__ wt)
{
  long row = blockIdx.x;
  const ushort* rp = p + row * 1472;
  ushort* op = wt + row * 1472;
  int t = threadIdx.x;
  __shared__ float buf[1444];
  __shared__ float redm[4], reds[4];
  float mx = -3.4e38f;
  for (int i = t; i < 1444; i += 256) { float v = h2f(rp[i]); buf[i] = v; mx = fmaxf(mx, v); }
  #pragma unroll
  for (int o = 32; o; o >>= 1) mx = fmaxf(mx, __shfl_down(mx, o));
  if ((t & 63) == 0) redm[t >> 6] = mx;
  __syncthreads();
  mx = fmaxf(fmaxf(redm[0], redm[1]), fmaxf(redm[2], redm[3]));
  float s = 0.f;
  for (int i = t; i < 1444; i += 256) { float v = expf(buf[i] - mx); buf[i] = v; s += v; }
  #pragma unroll
  for (int o = 32; o; o >>= 1) s += __shfl_down(s, o);
  if ((t & 63) == 0) reds[t >> 6] = s;
  __syncthreads();
  float inv = 1.f / (reds[0] + reds[1] + reds[2] + reds[3]);
  for (int i = t; i < 1472; i += 256)
    op[i] = f2h((i < 1444) ? buf[i] * inv : 0.f);
}

// step-2 (a=0,b=1) classed attention; sums 6 khvc K-slice partials
__global__ __launch_bounds__(256) void attn_b1(
    const ushort* __restrict__ qT, const float* __restrict__ khvcp,
    ushort* __restrict__ xaT)
{
  __shared__ float ks[2304];   // [tt*256 + c]
  __shared__ float vs[2304];
  __shared__ float es[256][10];
  int n = blockIdx.y;
  int q0 = blockIdx.x * 256;
  for (int i = threadIdx.x; i < 2304; i += 256) {
    int tt = i >> 8, c = i & 255;
    size_t base = (size_t)(n * 9 + tt) * 512;
    float sk = 0.f, sv = 0.f;
    #pragma unroll
    for (int s = 0; s < 6; ++s) {
      sk += khvcp[s * 36864 + base + c];
      sv += khvcp[s * 36864 + base + 256 + c];
    }
    ks[i] = sk; vs[i] = sv;
  }
  __syncthreads();
  int q = q0 + threadIdx.x;
  bool act = (q < 1600);
  float Lg[9] = {0.f,0.f,0.f,0.f,0.f,0.f,0.f,0.f,0.f};
  const ushort* qp = qT + (size_t)n * 409600 + (act ? (size_t)q * 256 : 0);
  for (int c8 = 0; c8 < 256; c8 += 8) {
    h8 v = *(const h8*)(const void*)(qp + c8);
    #pragma unroll
    for (int j = 0; j < 8; ++j) {
      float f = (float)v[j];
      #pragma unroll
      for (int tt = 0; tt < 9; ++tt) Lg[tt] += f * ks[tt * 256 + c8 + j];
    }
  }
  float mx = Lg[0];
  #pragma unroll
  for (int tt = 1; tt < 9; ++tt) mx = fmaxf(mx, Lg[tt]);
  float Z = 0.f;
  float e[9];
  #pragma unroll
  for (int tt = 0; tt < 9; ++tt) {
    float m = ((tt / 3) == 1 ? 36.f : 1.f) * ((tt % 3) == 1 ? 36.f : 1.f);
    e[tt] = act ? m * expf(Lg[tt] - mx) : 0.f;
    Z += e[tt];
  }
  float inv = act ? (1.f / Z) : 0.f;
  #pragma unroll
  for (int tt = 0; tt < 9; ++tt) es[threadIdx.x][tt] = e[tt] * inv;
  __syncthreads();
  int nact = 1600 - q0; if (nact > 256) nact = 256;
  int p = threadIdx.x;
  for (int qq = 0; qq < nact; ++qq) {
    float s = 0.f;
    #pragma unroll
    for (int tt = 0; tt < 9; ++tt) s += es[qq][tt] * vs[tt * 256 + p];
    xaT[(size_t)n * 1228800 + (size_t)(q0 + qq) * 768 + 512 + p] = f2h(s);
  }
}

// ---------------------------------------------------------------------------
extern "C" void kernel_launch(void* const* d_in, const int* in_sizes, int n_in,
                              void* d_out, int out_size, void* d_ws, size_t ws_size,
                              hipStream_t stream)
{
  const float* x     = (const float*)d_in[0];
  const float* h0    = (const float*)d_in[1];
  const float* w_px  = (const float*)d_in[2];
  const float* b_px  = (const float*)d_in[3];
  const float* w_qx  = (const float*)d_in[4];
  const float* w_qh  = (const float*)d_in[5];
  const float* w_kx  = (const float*)d_in[6];
  const float* w_kh  = (const float*)d_in[7];
  const float* w_vx  = (const float*)d_in[8];
  const float* w_vh  = (const float*)d_in[9];
  const float* w_z   = (const float*)d_in[10];
  const float* b_z   = (const float*)d_in[11];
  const float* w_h   = (const float*)d_in[12];
  const float* b_h   = (const float*)d_in[13];
  const float* w_out = (const float*)d_in[14];
  const float* b_out = (const float*)d_in[15];
  float* out = (float*)d_out;

  char* base = (char*)d_ws;
  size_t off = 0;
  auto alloc = [&](size_t bytes) -> char* {
    off = (off + 255) & ~(size_t)255;
    char* p = base + off; off += bytes; return p;
  };
  ushort* xaT   = (ushort*)alloc(19660800);         // [8][1600][768] fp16
  ushort* qT    = (ushort*)alloc(6553600);          // [8][1600][256]
  ushort* kxT   = (ushort*)alloc(5914624);          // [8][1444][256]
  ushort* vxp   = (ushort*)alloc(6029312);          // [8][256][1472]
  ushort* xT    = (ushort*)alloc(3276800);          // [12800][128]
  ushort* Wqk   = (ushort*)alloc(2359296);          // [512][2304] conv-K order
  ushort* Wv    = (ushort*)alloc(1179648);          // [256][2304] conv-K order
  ushort* Wkv   = (ushort*)alloc(2359296);          // [512][2304]: w_kh|w_vh
  ushort* Wzh   = (ushort*)alloc(524288);           // [512][512]: w_z|w_h
  ushort* wpx   = (ushort*)alloc(65536);            // [256][128]
  ushort* wout  = (ushort*)alloc(393216);           // [256][768]
  ushort* zp    = (ushort*)alloc(128);              // 64-ushort zero page
  ushort* GA    = (ushort*)alloc(331776);           // [72][2304] fp16
  ushort* AV    = (ushort*)alloc(73728);            // [72][512] fp16
  float*  pre72p= (float*)alloc(589824);            // [4][72][512] partials
  float*  khvcp = (float*)alloc(884736);            // [6][72][512] partials
  float*  qh1   = (float*)alloc(9216);
  float*  kh1   = (float*)alloc(1024);
  float*  vh1   = (float*)alloc(1024);
  float*  L0    = (float*)alloc(415872);            // [8][9][1444] raw logits
  float*  h1    = (float*)alloc(73728);
  off = (off + 255) & ~(size_t)255;
  char* chunk = base + off;
  long avail = (long)ws_size - (long)off;
  if (avail < 0) avail = 0;
  int an = (int)(avail / 9420800L); if (an < 1) an = 1; if (an > 8) an = 8;

  auto mk = [&](const ushort* A, long sAb, const ushort* B, long sBb,
                int M, int Nn, int K, int Krow, int mode, int gRow0, int swap,
                int aConv, int bConv,
                float* Y, long sYb, long sYm, int nPer, long sYb2,
                const float* bias, int biasN,
                ushort* Yh, long sYpb, long sYpm, long pOff, ushort* Y2h) {
    MgArgs g;
    g.A = A; g.sAb = sAb; g.B = B; g.sBb = sBb;
    g.M = M; g.Nn = Nn; g.K = K; g.Krow = Krow; g.mode = mode;
    g.gRow0 = gRow0; g.swap = swap; g.aConv = aConv; g.bConv = bConv;
    g.zp = zp;
    g.Y = Y; g.sYb = sYb; g.sYm = sYm; g.nPer = nPer; g.sYb2 = sYb2;
    g.bias = bias; g.biasN = biasN;
    g.Yh = Yh; g.sYpb = sYpb; g.sYpm = sYpm; g.pOff = pOff; g.Y2h = Y2h;
    return g;
  };
  const int BIG = 0x40000000;

  // ---- 1) fused prep (all conversions + reorders + pads) ----
  prep_all<<<dim3(20064), dim3(256), 0, stream>>>(
      x, w_qx, w_kx, w_vx, w_px, w_out, w_kh, w_vh, w_z, w_h,
      xT, Wqk, Wv, wpx, wout, Wkv, Wzh, zp, vxp);

  // ---- 2) xp-conv: A=xT[12800][128], B=wpx -> xaT cols 0..255 ----
  mg_xp<<<dim3(4, 200, 1), dim3(256), 0, stream>>>(mk(xT, 0, wpx, 0,
     12800, 256, 128, 128, 1, 0, 1, 0, 0,
     nullptr, 0, 0, 0, 0, b_px, 1,
     xaT, 0, 768, 0, nullptr));

  // ---- 3) direct shifted-tap convs (conv-K order) ----
  // qk on the 64x128 single-buf variant (converged best, ~60.5us)
  mgemm_w<<<dim3(4, 200, 1), dim3(256), 0, stream>>>(xaT, 0, Wqk, 0,
     12800, 512, 2304, 2304, 2, 0, 1, 1, 0, zp,
     nullptr, 0, 0, 0, 0, nullptr, 0,
     qT, 0, 0, 0, kxT);
  mg_v<<<dim3(4, 200, 1), dim3(256), 0, stream>>>(mk(Wv, 0, xaT, 0,
     256, 12800, 2304, 2304, 3, 0, 0, 0, 1,
     nullptr, 0, 0, 0, 0, nullptr, 0,
     vxp, 0, 0, 0, nullptr));

  // ---- 4) classed section (fused chain, R21) ----
  uniform_kv_kern<<<dim3(256, 11), dim3(64), 0, stream>>>(h0, w_qh, w_kh, w_vh, qh1, kh1, vh1);
  l0_logits<<<dim3(6, 8), dim3(256), 0, stream>>>(qh1, kxT, L0);
  a10_pv_av<<<dim3(9, 8), dim3(256), 0, stream>>>(L0, vxp, vh1, AV);
  // AV[72][512] x Wzh[512][512], 4 K-slices of 128 -> pre72p[4][72][512]
  mg_cls<<<dim3(2, 8, 4), dim3(256), 0, stream>>>(mk(AV, 128, Wzh, 128,
     72, 512, 128, 512, 0, 0, 0, 0, 0,
     pre72p, 36864, 512, BIG, 0, nullptr, 0,
     nullptr, 0, 0, 0, nullptr));
  gate_ew2<<<dim3(72), dim3(256), 0, stream>>>(pre72p, b_z, b_h, h0, h1);
  build_GA<<<dim3(648), dim3(256), 0, stream>>>(h1, GA);
  // GA[72][2304] x Wkv[512][2304], 6 K-slices of 384 -> khvcp[6][72][512]
  mg_cls<<<dim3(2, 8, 6), dim3(256), 0, stream>>>(mk(GA, 384, Wkv, 384,
     72, 512, 384, 2304, 0, 0, 0, 0, 0,
     khvcp, 36864, 512, BIG, 0, nullptr, 0,
     nullptr, 0, 0, 0, nullptr));
  attn_b1<<<dim3(7, 8), dim3(256), 0, stream>>>(qT, khvcp, xaT);

  // ---- 5) step-2 (0,0) full attention (fp16 logits) ----
  {
    ushort* scL16 = (ushort*)chunk;
    for (int nb0 = 0; nb0 < 8; nb0 += an) {
      int c = (8 - nb0 < an) ? (8 - nb0) : an;
      ushort* wt = (ushort*)(chunk + (long)c * 4710400);
      mg_lg<<<dim3(25, 23, c), dim3(256), 0, stream>>>(mk(qT + (long)nb0 * 409600, 409600,
         kxT + (long)nb0 * 369664, 369664,
         1600, 1444, 256, 256, 1, 0, 0, 0, 0,
         nullptr, 0, 0, 0, 0, nullptr, 0,
         scL16, 2355200, 1472, 0, nullptr));
      softmax_h16<<<dim3(c * 1600), dim3(256), 0, stream>>>(scL16, wt);
      mg_pv<<<dim3(25, 4, c), dim3(256), 0, stream>>>(mk(wt, 2355200,
         vxp + (long)nb0 * 376832, 376832,
         1600, 256, 1472, 1472, 1, 0, 0, 0, 0,
         nullptr, 0, 0, 0, 0, nullptr, 0,
         xaT + (long)nb0 * 1228800, 1228800, 768, 256, nullptr));
    }
  }

  // ---- 6) out-conv: A=wout[256][768], B=xaT rows -> fp32 NCHW ----
  mg_out<<<dim3(4, 200, 1), dim3(256), 0, stream>>>(mk(wout, 0, xaT, 0,
     256, 12800, 768, 768, 0, 0, 0, 0, 0,
     out, 0, 1600, 1600, 409600, b_out, 0,
     nullptr, 0, 0, 0, nullptr));
}

// Round 14
// 423.063 us; speedup vs baseline: 1.1823x; 1.0527x over previous
//
#include <hip/hip_runtime.h>
#include <math.h>

// ---------------------------------------------------------------------------
// 2-step recurrent attention cell, N=8, I=128, C=Hc=A=P=O=256, H=W=40
// (Q=1600), VALID 3x3 -> 38x38 (D=1444). fp32 reference.
//
// R0-R10: algebraic reductions, MFMA GEMMs, DMA staging + XOR swizzle,
// direct shifted-tap conv, fp16 single-plane, 72-row classed GEMMs.
// R11-R13 FAILED (journal). R14 WIN (529->460): 64x128 tile.
// R15/R16 FAILED: BK=128 / dbuf@48KB (occupancy loss dominates).
// R17 WIN (460->442): 64x64+static dbuf @32KB. R18: qk on 64x128 single-buf.
// R19 WIN (->436.6): counted-vmcnt T4 on 64x64 dbuf + named wrappers.
// R20 FAILED-BRANCH: qk dbuf@48KB (occupancy). qk CONVERGED ~60us (R14 geom).
// R21 NEUTRAL (437.2): classed-chain fusion (kept).
// R22 CONFOUNDED (500): control kernel mgemm_w moved 60->92us -- machine.
// R23 ANCHOR (445.4): R21 source reproduces historical mgemm_w signature
// (60us @ 680GB/s); R22 confirmed machine-confounded. Cross-container
// noise: equivalent configs measured 436.6/437.2/445.4 (+/-1%).
// R24: re-introduce R22 pieces SINGLY. This round: softmax_h16 vectorized
// only (h8 load/store, register-resident, masked 1444-tail; deletes LDS
// round-trip and ~8x the memory-op count on 12800 rows). mgemm_w is the
// control: if it moves >10%, discard the measurement.
// ---------------------------------------------------------------------------

typedef _Float16 f16;
typedef _Float16 h8 __attribute__((ext_vector_type(8)));   // 8 fp16 (4 VGPRs)
typedef __attribute__((ext_vector_type(4))) float f4;

__device__ __forceinline__ ushort f2h(float f) {
  union { f16 h; ushort u; } cv; cv.h = (f16)f; return cv.u;
}
__device__ __forceinline__ float h2f(ushort u) {
  union { ushort u; f16 h; } cv; cv.u = u; return (float)cv.h;
}

// ---------------- MFMA fp16 GEMM, 64x64 tile, counted-vmcnt dbuf -----------
// (R19 structure, unchanged.) C[m][n] = sum_k A[m][k]*B[n][k].
struct MgArgs {
  const ushort* A; long sAb;
  const ushort* B; long sBb;
  int M, Nn, K, Krow, mode, gRow0, swap, aConv, bConv;
  const ushort* zp;
  float* Y; long sYb, sYm; int nPer; long sYb2;
  const float* bias; int biasN;
  ushort* Yh; long sYpb, sYpm, pOff;
  ushort* Y2h;
};

__device__ __forceinline__ void mg_body(const MgArgs& g, ushort* lbase)
{
  const int bz = blockIdx.z;
  const ushort* __restrict__ A = g.A + (long)bz * g.sAb;
  const ushort* __restrict__ B = g.B + (long)bz * g.sBb;
  const int mb = g.swap ? blockIdx.y : blockIdx.x;
  const int nb = g.swap ? blockIdx.x : blockIdx.y;
  const int m0 = mb * 64, n0 = nb * 64;
  const int t = threadIdx.x;
  const int lane = t & 63, wv = t >> 6;
  const int r = lane & 15, qd = lane >> 4;
  const int wn = wv * 16;
  const int lrow = lane >> 3, lch = lane & 7;
  f4 acc[4];
  #pragma unroll
  for (int i = 0; i < 4; ++i) acc[i] = (f4){0.f, 0.f, 0.f, 0.f};

  const int cg8 = (lch ^ lrow) * 8;
  int aB[2], aY[2], aX[2]; long aO[2];
  int bB[2], bY[2], bX[2]; long bO[2];
  #pragma unroll
  for (int i = 0; i < 2; ++i) {        // A rows: wv*16 + i*8 + lrow (0..63)
    int gr = m0 + wv * 16 + i * 8 + lrow;
    if (g.aConv) {
      int n8 = gr / 1600, pos = gr - n8 * 1600;
      int py = pos / 40, px = pos - py * 40;
      aB[i] = n8 * 1600; aY[i] = py; aX[i] = px;
    } else { if (gr > g.M - 1) gr = g.M - 1; aO[i] = (long)gr * g.Krow; }
  }
  #pragma unroll
  for (int i = 0; i < 2; ++i) {        // B rows: wv*16 + i*8 + lrow (0..63)
    int gr = n0 + wv * 16 + i * 8 + lrow;
    if (g.bConv) {
      int n8 = gr / 1600, pos = gr - n8 * 1600;
      int py = pos / 40, px = pos - py * 40;
      bB[i] = n8 * 1600; bY[i] = py; bX[i] = px;
    } else { if (gr > g.Nn - 1) gr = g.Nn - 1; bO[i] = (long)gr * g.Krow; }
  }

  auto stage = [&](int ch, int lb) {
    int cb = ch / 9, tap = ch - cb * 9;       // conv-K: cb-major, tap-minor
    int tdy = tap / 3 - 1, tdx = tap - (tap / 3) * 3 - 1;
    int kin = cb << 6;
    int kc2 = ch << 6;
    #pragma unroll
    for (int i = 0; i < 2; ++i) {             // A (2 x 16B per thread)
      const ushort* p; size_t go;
      if (g.aConv) {
        int yy = aY[i] + tdy, xx = aX[i] + tdx;
        bool v = ((unsigned)yy < 40u) && ((unsigned)xx < 40u);
        if (v) { go = (size_t)(aB[i] + yy * 40 + xx) * 768 + kin + cg8; p = A; }
        else   { go = 0; p = g.zp; }
      } else { go = (size_t)(aO[i] + kc2 + cg8); p = A; }
      __builtin_amdgcn_global_load_lds(p + go, lbase + lb + wv * 1024 + i * 512, 16, 0, 0);
    }
    #pragma unroll
    for (int i = 0; i < 2; ++i) {             // B (2 x 16B per thread)
      const ushort* p; size_t go;
      if (g.bConv) {
        int yy = bY[i] + tdy, xx = bX[i] + tdx;
        bool v = ((unsigned)yy < 40u) && ((unsigned)xx < 40u);
        if (v) { go = (size_t)(bB[i] + yy * 40 + xx) * 768 + kin + cg8; p = B; }
        else   { go = 0; p = g.zp; }
      } else { go = (size_t)(bO[i] + kc2 + cg8); p = B; }
      __builtin_amdgcn_global_load_lds(p + go, lbase + lb + 4096 + wv * 1024 + i * 512, 16, 0, 0);
    }
  };

  auto compute = [&](int lb) {
    #pragma unroll
    for (int kk = 0; kk < 2; ++kk) {
      int off = (((kk << 2) + qd) ^ (r & 7)) << 3;
      h8 af[4], bf;
      #pragma unroll
      for (int mt = 0; mt < 4; ++mt)
        af[mt] = *(const h8*)&lbase[lb + (mt * 16 + r) * 64 + off];
      bf = *(const h8*)&lbase[lb + 4096 + (wn + r) * 64 + off];
      #pragma unroll
      for (int mt = 0; mt < 4; ++mt)
        acc[mt] = __builtin_amdgcn_mfma_f32_16x16x32_f16(af[mt], bf, acc[mt], 0, 0, 0);
    }
  };

  // counted-vmcnt 2-phase (T4): never drain vmcnt to 0 mid-loop.
  const int nch = g.K >> 6;
  stage(0, 0);                                  // out: ch0(4)
  int ch = 0;
  while (ch + 2 <= nch) {
    stage(ch + 1, 8192);                        // out: ch(4)+ch1(4)
    asm volatile("s_waitcnt vmcnt(4)" ::: "memory");   // ch landed
    __builtin_amdgcn_s_barrier();
    __builtin_amdgcn_sched_barrier(0);
    compute(0);
    __builtin_amdgcn_s_barrier();               // WAR: reads of b0 done
    __builtin_amdgcn_sched_barrier(0);
    if (ch + 2 < nch) {
      stage(ch + 2, 0);                         // out: ch1(<=4)+ch2(4)
      asm volatile("s_waitcnt vmcnt(4)" ::: "memory"); // ch+1 landed
    } else {
      asm volatile("s_waitcnt vmcnt(0)" ::: "memory"); // no new loads issued
    }
    __builtin_amdgcn_s_barrier();
    __builtin_amdgcn_sched_barrier(0);
    compute(8192);
    __builtin_amdgcn_s_barrier();               // WAR: reads of b1 done
    __builtin_amdgcn_sched_barrier(0);
    ch += 2;
  }
  if (ch < nch) {                               // odd tail (staged into b0)
    asm volatile("s_waitcnt vmcnt(0)" ::: "memory");
    __builtin_amdgcn_s_barrier();
    __builtin_amdgcn_sched_barrier(0);
    compute(0);
  }

  #pragma unroll
  for (int mt = 0; mt < 4; ++mt) {
    int nn = n0 + wn + r;
    if (nn >= g.Nn) continue;
    #pragma unroll
    for (int e = 0; e < 4; ++e) {
      int mm = m0 + mt * 16 + qd * 4 + e;
      if (mm >= g.M) continue;
      float v = acc[mt][e];
      if (g.mode == 0) {
        if (g.bias) v += g.bias[mm];
        int b2 = nn / g.nPer, nq = nn - b2 * g.nPer;
        g.Y[(size_t)bz * g.sYb + (size_t)b2 * g.sYb2 + (size_t)mm * g.sYm + nq] = v;
      } else if (g.mode == 1) {
        if (g.bias) v += g.bias[g.biasN ? nn : mm];
        g.Yh[(size_t)bz * g.sYpb + (size_t)mm * g.sYpm + nn + g.pOff] = f2h(v);
      } else if (g.mode == 2) {
        int gm = g.gRow0 + mm;
        int n8 = gm / 1600, q = gm - n8 * 1600;
        ushort h = f2h(v);
        if (nn < 256) {
          g.Yh[(size_t)n8 * 409600 + (size_t)q * 256 + nn] = h;
        } else {
          int qy = q / 40, qx = q - qy * 40;
          if (qy >= 1 && qy <= 38 && qx >= 1 && qx <= 38)
            g.Y2h[(size_t)n8 * 369664 + (size_t)((qy - 1) * 38 + qx - 1) * 256 + (nn - 256)] = h;
        }
      } else {   // mode 3
        int gn = g.gRow0 + nn;
        int n8 = gn / 1600, q = gn - n8 * 1600;
        int qy = q / 40, qx = q - qy * 40;
        if (qy >= 1 && qy <= 38 && qx >= 1 && qx <= 38)
          g.Yh[(size_t)n8 * 376832 + (size_t)mm * 1472 + (qy - 1) * 38 + qx - 1] = f2h(v);
      }
    }
  }
}

// named wrappers: one per call site for rocprof attribution
#define MG_KERN(name) \
__global__ __launch_bounds__(256) void name(MgArgs g) { \
  __shared__ ushort S[16384]; mg_body(g, S); }
MG_KERN(mg_xp)
MG_KERN(mg_v)
MG_KERN(mg_cls)
MG_KERN(mg_lg)
MG_KERN(mg_pv)
MG_KERN(mg_out)
#undef MG_KERN

// ---------------- MFMA fp16 GEMM, 64x128 tile, single-buf (R14) ------------
// qk-conv only. CONVERGED at ~60.5us across 6 tested structures: occupancy
// (24KB LDS, ~2.7 blocks/CU) beats every pipelining variant on this shape.
__global__ __launch_bounds__(256) void mgemm_w(
    const ushort* __restrict__ A, long sAb,
    const ushort* __restrict__ B, long sBb,
    int M, int Nn, int K, int Krow, int mode, int gRow0, int swap,
    int aConv, int bConv,
    const ushort* __restrict__ zp,
    float* __restrict__ Y, long sYb, long sYm, int nPer, long sYb2,
    const float* __restrict__ bias, int biasN,
    ushort* __restrict__ Yh, long sYpb, long sYpm, long pOff,
    ushort* __restrict__ Y2h)
{
  __shared__ ushort S[12288];   // SA[64][64] @ 0, SB[128][64] @ 4096 ; 24 KB
  const int bz = blockIdx.z;
  A += (long)bz * sAb;
  B += (long)bz * sBb;
  const int mb = swap ? blockIdx.y : blockIdx.x;
  const int nb = swap ? blockIdx.x : blockIdx.y;
  const int m0 = mb * 64, n0 = nb * 128;
  const int t = threadIdx.x;
  const int lane = t & 63, wv = t >> 6;
  const int r = lane & 15, qd = lane >> 4;
  const int wn = wv * 32;
  const int lrow = lane >> 3, lch = lane & 7;
  f4 acc[4][2];
  #pragma unroll
  for (int i = 0; i < 4; ++i)
    #pragma unroll
    for (int j = 0; j < 2; ++j) acc[i][j] = (f4){0.f, 0.f, 0.f, 0.f};

  const int cg8 = (lch ^ lrow) * 8;
  int aB[2], aY[2], aX[2]; long aO[2];
  int bB[4], bY[4], bX[4]; long bO[4];
  #pragma unroll
  for (int i = 0; i < 2; ++i) {        // A rows: wv*16 + i*8 + lrow (0..63)
    int gr = m0 + wv * 16 + i * 8 + lrow;
    if (aConv) {
      int n8 = gr / 1600, pos = gr - n8 * 1600;
      int py = pos / 40, px = pos - py * 40;
      aB[i] = n8 * 1600; aY[i] = py; aX[i] = px;
    } else { if (gr > M - 1) gr = M - 1; aO[i] = (long)gr * Krow; }
  }
  #pragma unroll
  for (int i = 0; i < 4; ++i) {        // B rows: wv*32 + i*8 + lrow (0..127)
    int gr = n0 + wv * 32 + i * 8 + lrow;
    if (bConv) {
      int n8 = gr / 1600, pos = gr - n8 * 1600;
      int py = pos / 40, px = pos - py * 40;
      bB[i] = n8 * 1600; bY[i] = py; bX[i] = px;
    } else { if (gr > Nn - 1) gr = Nn - 1; bO[i] = (long)gr * Krow; }
  }

  ushort* lbase = S;
  for (int kc = 0; kc < K; kc += 64) {
    __syncthreads();
    int ch = kc >> 6;
    int cb = ch / 9, tap = ch - cb * 9;       // conv-K: cb-major, tap-minor
    int tdy = tap / 3 - 1, tdx = tap - (tap / 3) * 3 - 1;
    int kin = cb << 6;
    #pragma unroll
    for (int i = 0; i < 2; ++i) {             // stage A (2 x 16B per thread)
      const ushort* p; size_t go;
      if (aConv) {
        int yy = aY[i] + tdy, xx = aX[i] + tdx;
        bool v = ((unsigned)yy < 40u) && ((unsigned)xx < 40u);
        if (v) { go = (size_t)(aB[i] + yy * 40 + xx) * 768 + kin + cg8; p = A; }
        else   { go = 0; p = zp; }
      } else { go = (size_t)(aO[i] + kc + cg8); p = A; }
      __builtin_amdgcn_global_load_lds(p + go, lbase + wv * 1024 + i * 512, 16, 0, 0);
    }
    #pragma unroll
    for (int i = 0; i < 4; ++i) {             // stage B (4 x 16B per thread)
      const ushort* p; size_t go;
      if (bConv) {
        int yy = bY[i] + tdy, xx = bX[i] + tdx;
        bool v = ((unsigned)yy < 40u) && ((unsigned)xx < 40u);
        if (v) { go = (size_t)(bB[i] + yy * 40 + xx) * 768 + kin + cg8; p = B; }
        else   { go = 0; p = zp; }
      } else { go = (size_t)(bO[i] + kc + cg8); p = B; }
      __builtin_amdgcn_global_load_lds(p + go, lbase + 4096 + wv * 2048 + i * 512, 16, 0, 0);
    }
    __syncthreads();
    #pragma unroll
    for (int kk = 0; kk < 2; ++kk) {
      int off = (((kk << 2) + qd) ^ (r & 7)) << 3;
      h8 af[4], bf[2];
      #pragma unroll
      for (int mt = 0; mt < 4; ++mt)
        af[mt] = *(const h8*)&lbase[(mt * 16 + r) * 64 + off];
      #pragma unroll
      for (int nt = 0; nt < 2; ++nt)
        bf[nt] = *(const h8*)&lbase[4096 + (wn + nt * 16 + r) * 64 + off];
      #pragma unroll
      for (int mt = 0; mt < 4; ++mt)
        #pragma unroll
        for (int nt = 0; nt < 2; ++nt)
          acc[mt][nt] = __builtin_amdgcn_mfma_f32_16x16x32_f16(af[mt], bf[nt], acc[mt][nt], 0, 0, 0);
    }
  }
  #pragma unroll
  for (int mt = 0; mt < 4; ++mt)
    #pragma unroll
    for (int nt = 0; nt < 2; ++nt) {
      int nn = n0 + wn + nt * 16 + r;
      if (nn >= Nn) continue;
      #pragma unroll
      for (int e = 0; e < 4; ++e) {
        int mm = m0 + mt * 16 + qd * 4 + e;
        if (mm >= M) continue;
        float v = acc[mt][nt][e];
        if (mode == 0) {
          if (bias) v += bias[mm];
          int b2 = nn / nPer, nq = nn - b2 * nPer;
          Y[(size_t)bz * sYb + (size_t)b2 * sYb2 + (size_t)mm * sYm + nq] = v;
        } else if (mode == 1) {
          if (bias) v += bias[biasN ? nn : mm];
          Yh[(size_t)bz * sYpb + (size_t)mm * sYpm + nn + pOff] = f2h(v);
        } else if (mode == 2) {
          int gm = gRow0 + mm;
          int n8 = gm / 1600, q = gm - n8 * 1600;
          ushort h = f2h(v);
          if (nn < 256) {
            Yh[(size_t)n8 * 409600 + (size_t)q * 256 + nn] = h;
          } else {
            int qy = q / 40, qx = q - qy * 40;
            if (qy >= 1 && qy <= 38 && qx >= 1 && qx <= 38)
              Y2h[(size_t)n8 * 369664 + (size_t)((qy - 1) * 38 + qx - 1) * 256 + (nn - 256)] = h;
          }
        } else {   // mode 3
          int gn = gRow0 + nn;
          int n8 = gn / 1600, q = gn - n8 * 1600;
          int qy = q / 40, qx = q - qy * 40;
          if (qy >= 1 && qy <= 38 && qx >= 1 && qx <= 38)
            Yh[(size_t)n8 * 376832 + (size_t)mm * 1472 + (qy - 1) * 38 + qx - 1] = f2h(v);
        }
      }
    }
}

// ---------------- fused prep: all weight/input conversions + pads ----------
// range-dispatched single kernel (replaces 8 small launches)
__global__ __launch_bounds__(256) void prep_all(
    const float* __restrict__ x,
    const float* __restrict__ w_qx, const float* __restrict__ w_kx,
    const float* __restrict__ w_vx,
    const float* __restrict__ w_px, const float* __restrict__ w_out,
    const float* __restrict__ w_kh, const float* __restrict__ w_vh,
    const float* __restrict__ w_z, const float* __restrict__ w_h,
    ushort* __restrict__ xT, ushort* __restrict__ Wqk, ushort* __restrict__ Wv,
    ushort* __restrict__ wpx, ushort* __restrict__ wout,
    ushort* __restrict__ Wkv, ushort* __restrict__ Wzh,
    ushort* __restrict__ zp, ushort* __restrict__ vxp)
{
  long gi = (long)blockIdx.x * 256 + threadIdx.x;
  if (gi < 64) zp[gi] = 0;
  long i = gi;
  if (i < 1638400) {                         // xT [12800][128] transpose-cvt
    int i1 = (int)(i & 127); long r = i >> 7;
    int q = (int)(r % 1600); int n8 = (int)(r / 1600);
    xT[i] = f2h(x[(long)n8 * 204800 + (long)i1 * 1600 + q]);
    return;
  }
  i -= 1638400;
  if (i < 1769472) {                         // Wqk/Wv conv-K reorder
    int o = (int)(i / 2304), k = (int)(i - (long)o * 2304);
    int cb = k / 576, rem = k - cb * 576;
    int tap = rem >> 6, ci = rem & 63;
    int si = (cb * 64 + ci) * 9 + tap;
    float f; ushort* d; int oo;
    if (o < 256)      { f = w_qx[o * 2304 + si];         d = Wqk; oo = o; }
    else if (o < 512) { f = w_kx[(o - 256) * 2304 + si]; d = Wqk; oo = o; }
    else              { f = w_vx[(o - 512) * 2304 + si]; d = Wv;  oo = o - 512; }
    d[oo * 2304 + k] = f2h(f);
    return;
  }
  i -= 1769472;
  if (i < 32768)  { wpx[i]  = f2h(w_px[i]);  return; }
  i -= 32768;
  if (i < 196608) { wout[i] = f2h(w_out[i]); return; }
  i -= 196608;
  if (i < 1179648) { Wkv[i] = f2h(i < 589824 ? w_kh[i] : w_vh[i - 589824]); return; }
  i -= 1179648;
  if (i < 262144)  { Wzh[i] = f2h(i < 131072 ? w_z[i] : w_h[i - 131072]); return; }
  i -= 262144;
  if (i < 57344) {                           // vxp pad cols 1444..1471
    int j = (int)(i % 28); int rr = (int)(i / 28);
    int c = rr % 256, n = rr / 256;
    vxp[(size_t)n * 376832 + (size_t)c * 1472 + 1444 + j] = 0;
  }
}

// step-1 uniform-h class tables
__global__ __launch_bounds__(64) void uniform_kv_kern(
    const float* __restrict__ h0, const float* __restrict__ w_qh,
    const float* __restrict__ w_kh, const float* __restrict__ w_vh,
    float* __restrict__ qh1, float* __restrict__ kh1, float* __restrict__ vh1)
{
  int a = blockIdx.x, j = blockIdx.y, t = threadIdx.x;
  const float* wsel = (j < 9) ? w_qh : (j == 9) ? w_kh : w_vh;
  bool dyok0 = true, dyok2 = true, dxok0 = true, dxok2 = true;
  if (j < 9) {
    int uy = j / 3, ux = j - uy * 3;
    dyok0 = (uy != 0); dyok2 = (uy != 2);
    dxok0 = (ux != 0); dxok2 = (ux != 2);
  }
  float acc = 0.f;
  for (int c = t; c < 256; c += 64) {
    const float* wp = wsel + a * 2304 + c * 9;
    float s = 0.f;
    #pragma unroll
    for (int dy = 0; dy < 3; ++dy) {
      if ((dy == 0 && !dyok0) || (dy == 2 && !dyok2)) continue;
      #pragma unroll
      for (int dx = 0; dx < 3; ++dx) {
        if ((dx == 0 && !dxok0) || (dx == 2 && !dxok2)) continue;
        s += wp[dy * 3 + dx];
      }
    }
    acc += s * h0[c];
  }
  #pragma unroll
  for (int o = 32; o; o >>= 1) acc += __shfl_down(acc, o);
  if (t == 0) {
    if (j < 9) qh1[j * 256 + a] = acc;
    else if (j == 9) kh1[a] = acc;
    else vh1[a] = acc;
  }
}

// L0[n][u][d] = sum_c qh1[u][c] * k_x[n][d][c]  (kxT fp16) -- raw logits
__global__ __launch_bounds__(256) void l0_logits(
    const float* __restrict__ qh1, const ushort* __restrict__ kxT,
    float* __restrict__ L0)
{
  __shared__ float qs[2304];
  int db = blockIdx.x, n = blockIdx.y;
  for (int i = threadIdx.x; i < 2304; i += 256) qs[i] = qh1[i];
  __syncthreads();
  int d = db * 256 + threadIdx.x;
  bool act = d < 1444;
  const ushort* vp = kxT + (size_t)n * 369664 + (act ? (size_t)d * 256 : 0);
  float acc[9] = {0.f,0.f,0.f,0.f,0.f,0.f,0.f,0.f,0.f};
  for (int c8 = 0; c8 < 256; c8 += 8) {
    h8 v = *(const h8*)(const void*)(vp + c8);
    #pragma unroll
    for (int j = 0; j < 8; ++j) {
      float f = (float)v[j];
      #pragma unroll
      for (int u = 0; u < 9; ++u) acc[u] += qs[u * 256 + c8 + j] * f;
    }
  }
  if (act)
    for (int u = 0; u < 9; ++u) L0[n * 12996 + u * 1444 + d] = acc[u];
}

// FUSED (R21): row-softmax over raw L0[n][u][:1444] + PV vs vxp + AV write.
__global__ __launch_bounds__(256) void a10_pv_av(
    const float* __restrict__ L0, const ushort* __restrict__ vxp,
    const float* __restrict__ vh1, ushort* __restrict__ AV)
{
  int u = blockIdx.x, n = blockIdx.y;
  __shared__ float wts[1472];
  __shared__ float redm[4], reds[4];
  const float* wrow = L0 + n * 12996 + u * 1444;
  int t = threadIdx.x;
  float mx = -3.4e38f;
  for (int i = t; i < 1444; i += 256) { float v = wrow[i]; wts[i] = v; mx = fmaxf(mx, v); }
  #pragma unroll
  for (int o = 32; o; o >>= 1) mx = fmaxf(mx, __shfl_down(mx, o));
  if ((t & 63) == 0) redm[t >> 6] = mx;
  __syncthreads();
  mx = fmaxf(fmaxf(redm[0], redm[1]), fmaxf(redm[2], redm[3]));
  float s = 0.f;
  for (int i = t; i < 1444; i += 256) { float v = expf(wts[i] - mx); wts[i] = v; s += v; }
  #pragma unroll
  for (int o = 32; o; o >>= 1) s += __shfl_down(s, o);
  if ((t & 63) == 0) reds[t >> 6] = s;
  __syncthreads();
  float inv = 1.f / (reds[0] + reds[1] + reds[2] + reds[3]);
  for (int i = t; i < 1444; i += 256) wts[i] *= inv;
  if (t < 28) wts[1444 + t] = 0.f;
  __syncthreads();
  int p = t;
  const ushort* vp = vxp + (size_t)n * 376832 + (size_t)p * 1472;
  float acc = 0.f;
  for (int d8 = 0; d8 < 1472; d8 += 8) {
    h8 v = *(const h8*)(const void*)(vp + d8);
    #pragma unroll
    for (int j = 0; j < 8; ++j) acc += wts[d8 + j] * (float)v[j];
  }
  size_t row = (size_t)(n * 9 + u);
  AV[row * 512 + p] = f2h(acc);
  AV[row * 512 + 256 + p] = f2h(vh1[p]);
}

// gate tail: sum 4 K-slice partials pre72p[4][72][512], bias, GRU blend
__global__ __launch_bounds__(256) void gate_ew2(
    const float* __restrict__ pre72p, const float* __restrict__ b_z,
    const float* __restrict__ b_h, const float* __restrict__ h0,
    float* __restrict__ h1)
{
  int i = blockIdx.x * 256 + threadIdx.x;
  if (i >= 72 * 256) return;
  int row = i >> 8, c = i & 255;
  float zs = 0.f, hs = 0.f;
  #pragma unroll
  for (int s = 0; s < 4; ++s) {
    zs += pre72p[s * 36864 + row * 512 + c];
    hs += pre72p[s * 36864 + row * 512 + 256 + c];
  }
  float z = 1.f / (1.f + expf(-(zs + b_z[c])));
  float hv = tanhf(hs + b_h[c]);
  int n = row / 9, u = row - n * 9;
  h1[n * 2304 + c * 9 + u] = z * h0[c] + (1.f - z) * hv;
}

// GA[72][2304] fp16: classed im2col of h1; k = c*9+tap (plain weight layout)
__global__ __launch_bounds__(256) void build_GA(
    const float* __restrict__ h1, ushort* __restrict__ GA)
{
  int i = blockIdx.x * 256 + threadIdx.x;
  if (i >= 72 * 2304) return;
  int row = i / 2304, k = i - row * 2304;
  int c = k / 9, tap = k - c * 9;
  int u = row % 9;
  int ty = u / 3, tx = u - ty * 3;
  int dy = tap / 3, dx = tap - dy * 3;
  int uy = (ty == 0) ? (dy == 0 ? 0 : 1) : (ty == 2) ? (dy == 2 ? 2 : 1) : 1;
  int ux = (tx == 0) ? (dx == 0 ? 0 : 1) : (tx == 2) ? (dx == 2 ? 2 : 1) : 1;
  GA[i] = f2h(h1[(row / 9) * 2304 + c * 9 + uy * 3 + ux]);
}

// softmax over 1444 fp16 logits (row stride 1472) -> fp16 rows (1472, padded)
// R24: vectorized h8 load/store, register-resident, masked 1444-tail.
// (Cols 1444..1471 of the INPUT are never written by mg_lg -> masked out of
// max/sum; output writes full 1472 with zeros in the pad via the exp mask.)
__global__ __launch_bounds__(256) void softmax_h16(
    const ushort* __restrict__ p, ushort* __restrict__ wt)
{
  long row = blockIdx.x;
  const ushort* rp = p + row * 1472;
  ushort* op = wt + row * 1472;
  int t = threadIdx.x;
  __shared__ float redm[4], reds[4];
  float v[8];
  const bool act = t < 184;            // 184*8 = 1472
  const int base = t * 8;
  float mx = -3.4e38f;
  if (act) {
    h8 hv = *(const h8*)(const void*)(rp + base);
    #pragma unroll
    for (int j = 0; j < 8; ++j) {
      v[j] = (base + j < 1444) ? (float)hv[j] : -3.4e38f;
      mx = fmaxf(mx, v[j]);
    }
  }
  #pragma unroll
  for (int o = 32; o; o >>= 1) mx = fmaxf(mx, __shfl_down(mx, o));
  if ((t & 63) == 0) redm[t >> 6] = mx;
  __syncthreads();
  mx = fmaxf(fmaxf(redm[0], redm[1]), fmaxf(redm[2], redm[3]));
  float s = 0.f;
  if (act) {
    #pragma unroll
    for (int j = 0; j < 8; ++j) {
      float e = (base + j < 1444) ? expf(v[j] - mx) : 0.f;
      v[j] = e; s += e;
    }
  }
  #pragma unroll
  for (int o = 32; o; o >>= 1) s += __shfl_down(s, o);
  if ((t & 63) == 0) reds[t >> 6] = s;
  __syncthreads();
  float inv = 1.f / (reds[0] + reds[1] + reds[2] + reds[3]);
  if (act) {
    h8 hw;
    #pragma unroll
    for (int j = 0; j < 8; ++j) hw[j] = (f16)(v[j] * inv);
    *(h8*)(void*)(op + base) = hw;
  }
}

// step-2 (a=0,b=1) classed attention; sums 6 khvc K-slice partials
__global__ __launch_bounds__(256) void attn_b1(
    const ushort* __restrict__ qT, const float* __restrict__ khvcp,
    ushort* __restrict__ xaT)
{
  __shared__ float ks[2304];   // [tt*256 + c]
  __shared__ float vs[2304];
  __shared__ float es[256][10];
  int n = blockIdx.y;
  int q0 = blockIdx.x * 256;
  for (int i = threadIdx.x; i < 2304; i += 256) {
    int tt = i >> 8, c = i & 255;
    size_t base = (size_t)(n * 9 + tt) * 512;
    float sk = 0.f, sv = 0.f;
    #pragma unroll
    for (int s = 0; s < 6; ++s) {
      sk += khvcp[s * 36864 + base + c];
      sv += khvcp[s * 36864 + base + 256 + c];
    }
    ks[i] = sk; vs[i] = sv;
  }
  __syncthreads();
  int q = q0 + threadIdx.x;
  bool act = (q < 1600);
  float Lg[9] = {0.f,0.f,0.f,0.f,0.f,0.f,0.f,0.f,0.f};
  const ushort* qp = qT + (size_t)n * 409600 + (act ? (size_t)q * 256 : 0);
  for (int c8 = 0; c8 < 256; c8 += 8) {
    h8 v = *(const h8*)(const void*)(qp + c8);
    #pragma unroll
    for (int j = 0; j < 8; ++j) {
      float f = (float)v[j];
      #pragma unroll
      for (int tt = 0; tt < 9; ++tt) Lg[tt] += f * ks[tt * 256 + c8 + j];
    }
  }
  float mx = Lg[0];
  #pragma unroll
  for (int tt = 1; tt < 9; ++tt) mx = fmaxf(mx, Lg[tt]);
  float Z = 0.f;
  float e[9];
  #pragma unroll
  for (int tt = 0; tt < 9; ++tt) {
    float m = ((tt / 3) == 1 ? 36.f : 1.f) * ((tt % 3) == 1 ? 36.f : 1.f);
    e[tt] = act ? m * expf(Lg[tt] - mx) : 0.f;
    Z += e[tt];
  }
  float inv = act ? (1.f / Z) : 0.f;
  #pragma unroll
  for (int tt = 0; tt < 9; ++tt) es[threadIdx.x][tt] = e[tt] * inv;
  __syncthreads();
  int nact = 1600 - q0; if (nact > 256) nact = 256;
  int p = threadIdx.x;
  for (int qq = 0; qq < nact; ++qq) {
    float s = 0.f;
    #pragma unroll
    for (int tt = 0; tt < 9; ++tt) s += es[qq][tt] * vs[tt * 256 + p];
    xaT[(size_t)n * 1228800 + (size_t)(q0 + qq) * 768 + 512 + p] = f2h(s);
  }
}

// ---------------------------------------------------------------------------
extern "C" void kernel_launch(void* const* d_in, const int* in_sizes, int n_in,
                              void* d_out, int out_size, void* d_ws, size_t ws_size,
                              hipStream_t stream)
{
  const float* x     = (const float*)d_in[0];
  const float* h0    = (const float*)d_in[1];
  const float* w_px  = (const float*)d_in[2];
  const float* b_px  = (const float*)d_in[3];
  const float* w_qx  = (const float*)d_in[4];
  const float* w_qh  = (const float*)d_in[5];
  const float* w_kx  = (const float*)d_in[6];
  const float* w_kh  = (const float*)d_in[7];
  const float* w_vx  = (const float*)d_in[8];
  const float* w_vh  = (const float*)d_in[9];
  const float* w_z   = (const float*)d_in[10];
  const float* b_z   = (const float*)d_in[11];
  const float* w_h   = (const float*)d_in[12];
  const float* b_h   = (const float*)d_in[13];
  const float* w_out = (const float*)d_in[14];
  const float* b_out = (const float*)d_in[15];
  float* out = (float*)d_out;

  char* base = (char*)d_ws;
  size_t off = 0;
  auto alloc = [&](size_t bytes) -> char* {
    off = (off + 255) & ~(size_t)255;
    char* p = base + off; off += bytes; return p;
  };
  ushort* xaT   = (ushort*)alloc(19660800);         // [8][1600][768] fp16
  ushort* qT    = (ushort*)alloc(6553600);          // [8][1600][256]
  ushort* kxT   = (ushort*)alloc(5914624);          // [8][1444][256]
  ushort* vxp   = (ushort*)alloc(6029312);          // [8][256][1472]
  ushort* xT    = (ushort*)alloc(3276800);          // [12800][128]
  ushort* Wqk   = (ushort*)alloc(2359296);          // [512][2304] conv-K order
  ushort* Wv    = (ushort*)alloc(1179648);          // [256][2304] conv-K order
  ushort* Wkv   = (ushort*)alloc(2359296);          // [512][2304]: w_kh|w_vh
  ushort* Wzh   = (ushort*)alloc(524288);           // [512][512]: w_z|w_h
  ushort* wpx   = (ushort*)alloc(65536);            // [256][128]
  ushort* wout  = (ushort*)alloc(393216);           // [256][768]
  ushort* zp    = (ushort*)alloc(128);              // 64-ushort zero page
  ushort* GA    = (ushort*)alloc(331776);           // [72][2304] fp16
  ushort* AV    = (ushort*)alloc(73728);            // [72][512] fp16
  float*  pre72p= (float*)alloc(589824);            // [4][72][512] partials
  float*  khvcp = (float*)alloc(884736);            // [6][72][512] partials
  float*  qh1   = (float*)alloc(9216);
  float*  kh1   = (float*)alloc(1024);
  float*  vh1   = (float*)alloc(1024);
  float*  L0    = (float*)alloc(415872);            // [8][9][1444] raw logits
  float*  h1    = (float*)alloc(73728);
  off = (off + 255) & ~(size_t)255;
  char* chunk = base + off;
  long avail = (long)ws_size - (long)off;
  if (avail < 0) avail = 0;
  int an = (int)(avail / 9420800L); if (an < 1) an = 1; if (an > 8) an = 8;

  auto mk = [&](const ushort* A, long sAb, const ushort* B, long sBb,
                int M, int Nn, int K, int Krow, int mode, int gRow0, int swap,
                int aConv, int bConv,
                float* Y, long sYb, long sYm, int nPer, long sYb2,
                const float* bias, int biasN,
                ushort* Yh, long sYpb, long sYpm, long pOff, ushort* Y2h) {
    MgArgs g;
    g.A = A; g.sAb = sAb; g.B = B; g.sBb = sBb;
    g.M = M; g.Nn = Nn; g.K = K; g.Krow = Krow; g.mode = mode;
    g.gRow0 = gRow0; g.swap = swap; g.aConv = aConv; g.bConv = bConv;
    g.zp = zp;
    g.Y = Y; g.sYb = sYb; g.sYm = sYm; g.nPer = nPer; g.sYb2 = sYb2;
    g.bias = bias; g.biasN = biasN;
    g.Yh = Yh; g.sYpb = sYpb; g.sYpm = sYpm; g.pOff = pOff; g.Y2h = Y2h;
    return g;
  };
  const int BIG = 0x40000000;

  // ---- 1) fused prep (all conversions + reorders + pads) ----
  prep_all<<<dim3(20064), dim3(256), 0, stream>>>(
      x, w_qx, w_kx, w_vx, w_px, w_out, w_kh, w_vh, w_z, w_h,
      xT, Wqk, Wv, wpx, wout, Wkv, Wzh, zp, vxp);

  // ---- 2) xp-conv: A=xT[12800][128], B=wpx -> xaT cols 0..255 ----
  mg_xp<<<dim3(4, 200, 1), dim3(256), 0, stream>>>(mk(xT, 0, wpx, 0,
     12800, 256, 128, 128, 1, 0, 1, 0, 0,
     nullptr, 0, 0, 0, 0, b_px, 1,
     xaT, 0, 768, 0, nullptr));

  // ---- 3) direct shifted-tap convs (conv-K order) ----
  // qk on the 64x128 single-buf variant (converged best, ~60.5us)
  mgemm_w<<<dim3(4, 200, 1), dim3(256), 0, stream>>>(xaT, 0, Wqk, 0,
     12800, 512, 2304, 2304, 2, 0, 1, 1, 0, zp,
     nullptr, 0, 0, 0, 0, nullptr, 0,
     qT, 0, 0, 0, kxT);
  mg_v<<<dim3(4, 200, 1), dim3(256), 0, stream>>>(mk(Wv, 0, xaT, 0,
     256, 12800, 2304, 2304, 3, 0, 0, 0, 1,
     nullptr, 0, 0, 0, 0, nullptr, 0,
     vxp, 0, 0, 0, nullptr));

  // ---- 4) classed section (fused chain, R21) ----
  uniform_kv_kern<<<dim3(256, 11), dim3(64), 0, stream>>>(h0, w_qh, w_kh, w_vh, qh1, kh1, vh1);
  l0_logits<<<dim3(6, 8), dim3(256), 0, stream>>>(qh1, kxT, L0);
  a10_pv_av<<<dim3(9, 8), dim3(256), 0, stream>>>(L0, vxp, vh1, AV);
  // AV[72][512] x Wzh[512][512], 4 K-slices of 128 -> pre72p[4][72][512]
  mg_cls<<<dim3(2, 8, 4), dim3(256), 0, stream>>>(mk(AV, 128, Wzh, 128,
     72, 512, 128, 512, 0, 0, 0, 0, 0,
     pre72p, 36864, 512, BIG, 0, nullptr, 0,
     nullptr, 0, 0, 0, nullptr));
  gate_ew2<<<dim3(72), dim3(256), 0, stream>>>(pre72p, b_z, b_h, h0, h1);
  build_GA<<<dim3(648), dim3(256), 0, stream>>>(h1, GA);
  // GA[72][2304] x Wkv[512][2304], 6 K-slices of 384 -> khvcp[6][72][512]
  mg_cls<<<dim3(2, 8, 6), dim3(256), 0, stream>>>(mk(GA, 384, Wkv, 384,
     72, 512, 384, 2304, 0, 0, 0, 0, 0,
     khvcp, 36864, 512, BIG, 0, nullptr, 0,
     nullptr, 0, 0, 0, nullptr));
  attn_b1<<<dim3(7, 8), dim3(256), 0, stream>>>(qT, khvcp, xaT);

  // ---- 5) step-2 (0,0) full attention (fp16 logits) ----
  {
    ushort* scL16 = (ushort*)chunk;
    for (int nb0 = 0; nb0 < 8; nb0 += an) {
      int c = (8 - nb0 < an) ? (8 - nb0) : an;
      ushort* wt = (ushort*)(chunk + (long)c * 4710400);
      mg_lg<<<dim3(25, 23, c), dim3(256), 0, stream>>>(mk(qT + (long)nb0 * 409600, 409600,
         kxT + (long)nb0 * 369664, 369664,
         1600, 1444, 256, 256, 1, 0, 0, 0, 0,
         nullptr, 0, 0, 0, 0, nullptr, 0,
         scL16, 2355200, 1472, 0, nullptr));
      softmax_h16<<<dim3(c * 1600), dim3(256), 0, stream>>>(scL16, wt);
      mg_pv<<<dim3(25, 4, c), dim3(256), 0, stream>>>(mk(wt, 2355200,
         vxp + (long)nb0 * 376832, 376832,
         1600, 256, 1472, 1472, 1, 0, 0, 0, 0,
         nullptr, 0, 0, 0, 0, nullptr, 0,
         xaT + (long)nb0 * 1228800, 1228800, 768, 256, nullptr));
    }
  }

  // ---- 6) out-conv: A=wout[256][768], B=xaT rows -> fp32 NCHW ----
  mg_out<<<dim3(4, 200, 1), dim3(256), 0, stream>>>(mk(wout, 0, xaT, 0,
     256, 12800, 768, 768, 0, 0, 0, 0, 0,
     out, 0, 1600, 1600, 409600, b_out, 0,
     nullptr, 0, 0, 0, nullptr));
}